// Round 1
// baseline (771.678 us; speedup 1.0000x reference)
//
#include <hip/hip_runtime.h>
#include <stdint.h>
#include <stddef.h>

// Problem constants (B=2,S=2048,D=1024,H=16,HD=64)
#define SCALE_LOG2E 11.541560327111707f   // 8 * log2(e): scores*8, softmax in exp2 domain

typedef __attribute__((ext_vector_type(8))) __bf16 bf16x8;
typedef __attribute__((ext_vector_type(4))) float f32x4;

#if __has_builtin(__builtin_amdgcn_exp2f)
#define EXP2F(x) __builtin_amdgcn_exp2f(x)
#else
#define EXP2F(x) exp2f(x)
#endif

__device__ __forceinline__ f32x4 mfma_bf16(bf16x8 a, bf16x8 b, f32x4 c) {
  return __builtin_amdgcn_mfma_f32_16x16x32_bf16(a, b, c, 0, 0, 0);
}

__device__ __forceinline__ unsigned short f2bf(float f) {
  unsigned int u = __builtin_bit_cast(unsigned int, f);
  u += 0x7fffu + ((u >> 16) & 1u);           // RNE
  return (unsigned short)(u >> 16);
}
__device__ __forceinline__ float bf2f(unsigned short b) {
  unsigned int u = ((unsigned int)b) << 16;
  return __builtin_bit_cast(float, u);
}

// async global->LDS, 16B per lane. LDS dest is wave-uniform base + lane*16.
__device__ __forceinline__ void async16(const void* g, void* lds) {
  __builtin_amdgcn_global_load_lds(
      (const __attribute__((address_space(1))) unsigned int*)g,
      (__attribute__((address_space(3))) unsigned int*)lds, 16, 0, 0);
}

// ---------------- conversion / splitting ----------------
// 3-way split: f = hi + mid + lo (each bf16), representation err ~2^-27 |f|.
__global__ void split3_kernel(const float* __restrict__ src,
                              unsigned short* __restrict__ dh,
                              unsigned short* __restrict__ dm,
                              unsigned short* __restrict__ dl, int n4) {
  int i = blockIdx.x * blockDim.x + threadIdx.x;
  if (i >= n4) return;
  float4 v = ((const float4*)src)[i];
  float vv[4] = {v.x, v.y, v.z, v.w};
  unsigned short hs[4], ms[4], ls[4];
#pragma unroll
  for (int c = 0; c < 4; c++) {
    float f = vv[c];
    unsigned short h = f2bf(f);
    float r1 = f - bf2f(h);           // exact (Sterbenz)
    unsigned short m = f2bf(r1);
    float r2 = r1 - bf2f(m);          // exact
    unsigned short l = f2bf(r2);
    hs[c] = h; ms[c] = m; ls[c] = l;
  }
  ((ushort4*)dh)[i] = make_ushort4(hs[0], hs[1], hs[2], hs[3]);
  ((ushort4*)dm)[i] = make_ushort4(ms[0], ms[1], ms[2], ms[3]);
  ((ushort4*)dl)[i] = make_ushort4(ls[0], ls[1], ls[2], ls[3]);
}

__global__ void cvt_kernel(const float* __restrict__ src,
                           unsigned short* __restrict__ dst, int n4) {
  int i = blockIdx.x * blockDim.x + threadIdx.x;
  if (i >= n4) return;
  float4 v = ((const float4*)src)[i];
  ((ushort4*)dst)[i] = make_ushort4(f2bf(v.x), f2bf(v.y), f2bf(v.z), f2bf(v.w));
}

// ---------------- Q/K projection: 3-plane split GEMM ----------------
// Y[m,n] = sum_k X[m,k] * W[n,k] + bias[n]; 128x128x32 tile, 4 waves.
// z=0 -> Q (bias bq), z=1 -> K (bias bk). Output: 3 bf16 planes, [B,H,S,HD].
__global__ __launch_bounds__(256) void gemm_qk(
    const unsigned short* __restrict__ Xbase,   // z-stride 3*4194304, plane stride 4194304
    const unsigned short* __restrict__ Wbase,   // z-stride 3*1048576, plane stride 1048576
    const float* __restrict__ bq, const float* __restrict__ bk,
    unsigned short* __restrict__ Obase)         // z-stride 3*4194304, plane stride 4194304
{
  __shared__ unsigned short LA[3][4096];
  __shared__ unsigned short LB[3][4096];
  const int z = blockIdx.z;
  const int tid = threadIdx.x;
  const int lane = tid & 63;
  const int wv = tid >> 6;
  const int wm = wv >> 1, wn = wv & 1;
  const int rl = lane & 15, qd = lane >> 4;
  const int m0 = blockIdx.y * 128, n0 = blockIdx.x * 128;

  const unsigned short* A0 = Xbase + (size_t)z * 12582912;
  const unsigned short* W0 = Wbase + (size_t)z * 3145728;
  const float* bias = z ? bk : bq;
  unsigned short* O0 = Obase + (size_t)z * 12582912;

  f32x4 acc[4][4];
#pragma unroll
  for (int i = 0; i < 4; i++)
#pragma unroll
    for (int j = 0; j < 4; j++) acc[i][j] = f32x4{0.f, 0.f, 0.f, 0.f};

  const int srow = wv * 32 + (lane >> 2);
  const int scol = (lane & 3) * 8;

  for (int k0 = 0; k0 < 1024; k0 += 32) {
#pragma unroll
    for (int p = 0; p < 3; p++) {
      const unsigned short* ga = A0 + (size_t)p * 4194304 + (size_t)(m0 + srow) * 1024 + k0 + scol;
      async16(ga, &LA[p][wv * 1024]);
      async16(ga + 16 * 1024, &LA[p][wv * 1024 + 512]);
      const unsigned short* gb = W0 + (size_t)p * 1048576 + (size_t)(n0 + srow) * 1024 + k0 + scol;
      async16(gb, &LB[p][wv * 1024]);
      async16(gb + 16 * 1024, &LB[p][wv * 1024 + 512]);
    }
    __syncthreads();
    bf16x8 ah[4], am[4], al[4];
#pragma unroll
    for (int i = 0; i < 4; i++) {
      int ro = (wm * 64 + i * 16 + rl) * 32 + qd * 8;
      ah[i] = *(const bf16x8*)&LA[0][ro];
      am[i] = *(const bf16x8*)&LA[1][ro];
      al[i] = *(const bf16x8*)&LA[2][ro];
    }
#pragma unroll
    for (int j = 0; j < 4; j++) {
      int ro = (wn * 64 + j * 16 + rl) * 32 + qd * 8;
      bf16x8 bh = *(const bf16x8*)&LB[0][ro];
      bf16x8 bm = *(const bf16x8*)&LB[1][ro];
      bf16x8 bl = *(const bf16x8*)&LB[2][ro];
#pragma unroll
      for (int i = 0; i < 4; i++) {
        f32x4 a = acc[i][j];
        a = mfma_bf16(ah[i], bh, a);
        a = mfma_bf16(ah[i], bm, a);
        a = mfma_bf16(am[i], bh, a);
        a = mfma_bf16(am[i], bm, a);
        a = mfma_bf16(ah[i], bl, a);
        a = mfma_bf16(al[i], bh, a);
        acc[i][j] = a;
      }
    }
    __syncthreads();
  }

  // epilogue: +bias, re-split fp32 -> 3 bf16 planes, heads layout [B,H,S,HD]
#pragma unroll
  for (int j = 0; j < 4; j++) {
    const int nn = n0 + wn * 64 + j * 16 + rl;
    const float bj = bias[nn];
    const int hh = nn >> 6, e = nn & 63;
#pragma unroll
    for (int i = 0; i < 4; i++) {
      const int mm = m0 + wm * 64 + i * 16 + qd * 4;
      const int b = mm >> 11;
#pragma unroll
      for (int r = 0; r < 4; r++) {
        const int s = (mm + r) & 2047;
        size_t idx = ((size_t)((b * 16 + hh) * 2048 + s) << 6) + e;
        float v = acc[i][j][r] + bj;
        unsigned short h = f2bf(v);
        float r1 = v - bf2f(h);
        unsigned short m2 = f2bf(r1);
        float r2 = r1 - bf2f(m2);
        unsigned short l2 = f2bf(r2);
        O0[idx] = h;
        O0[idx + 4194304] = m2;
        O0[idx + 8388608] = l2;
      }
    }
  }
}

// ---------------- V projection: plain bf16 GEMM, writes V^T [B,H,HD,S] ----------------
__global__ __launch_bounds__(256) void gemm_v(
    const unsigned short* __restrict__ A0,
    const unsigned short* __restrict__ W0,
    const float* __restrict__ bias,
    unsigned short* __restrict__ Vt)
{
  __shared__ unsigned short LA[4096];
  __shared__ unsigned short LB[4096];
  const int tid = threadIdx.x;
  const int lane = tid & 63;
  const int wv = tid >> 6;
  const int wm = wv >> 1, wn = wv & 1;
  const int rl = lane & 15, qd = lane >> 4;
  const int m0 = blockIdx.y * 128, n0 = blockIdx.x * 128;

  f32x4 acc[4][4];
#pragma unroll
  for (int i = 0; i < 4; i++)
#pragma unroll
    for (int j = 0; j < 4; j++) acc[i][j] = f32x4{0.f, 0.f, 0.f, 0.f};

  const int srow = wv * 32 + (lane >> 2);
  const int scol = (lane & 3) * 8;

  for (int k0 = 0; k0 < 1024; k0 += 32) {
    const unsigned short* ga = A0 + (size_t)(m0 + srow) * 1024 + k0 + scol;
    async16(ga, &LA[wv * 1024]);
    async16(ga + 16 * 1024, &LA[wv * 1024 + 512]);
    const unsigned short* gb = W0 + (size_t)(n0 + srow) * 1024 + k0 + scol;
    async16(gb, &LB[wv * 1024]);
    async16(gb + 16 * 1024, &LB[wv * 1024 + 512]);
    __syncthreads();
    bf16x8 af[4], bfr[4];
#pragma unroll
    for (int i = 0; i < 4; i++) af[i] = *(const bf16x8*)&LA[(wm * 64 + i * 16 + rl) * 32 + qd * 8];
#pragma unroll
    for (int j = 0; j < 4; j++) bfr[j] = *(const bf16x8*)&LB[(wn * 64 + j * 16 + rl) * 32 + qd * 8];
#pragma unroll
    for (int i = 0; i < 4; i++)
#pragma unroll
      for (int j = 0; j < 4; j++) acc[i][j] = mfma_bf16(af[i], bfr[j], acc[i][j]);
    __syncthreads();
  }

#pragma unroll
  for (int j = 0; j < 4; j++) {
    const int nn = n0 + wn * 64 + j * 16 + rl;
    const float bj = bias[nn];
    const int hh = nn >> 6, e = nn & 63;
#pragma unroll
    for (int i = 0; i < 4; i++) {
      const int mm = m0 + wm * 64 + i * 16 + qd * 4;
      const int b = mm >> 11, s = mm & 2047;
      ushort4 pk = make_ushort4(f2bf(acc[i][j][0] + bj), f2bf(acc[i][j][1] + bj),
                                f2bf(acc[i][j][2] + bj), f2bf(acc[i][j][3] + bj));
      *(ushort4*)(Vt + (((size_t)((b * 16 + hh) * 64 + e)) << 11) + s) = pk;
    }
  }
}

// ---------------- flash attention ----------------
// grid: (S/64, B*H), block 256 (4 waves x 16 q-rows). KV tiles of 128.
__global__ __launch_bounds__(256) void attn_kernel(
    const unsigned short* __restrict__ Qb,   // 3 planes, stride 4194304, [B,H,S,HD]
    const unsigned short* __restrict__ Kb,   // 3 planes
    const unsigned short* __restrict__ Vt,   // [B,H,HD,S]
    unsigned short* __restrict__ Xo)         // [B,S,D] bf16
{
  __shared__ unsigned short Pl[4][16][136];  // pad 128->136 to break LDS bank stride
  const int tid = threadIdx.x;
  const int lane = tid & 63;
  const int wv = tid >> 6;
  const int rl = lane & 15, qd = lane >> 4;
  const int bh = blockIdx.y;
  const int q0 = blockIdx.x * 64 + wv * 16;

  const size_t qoff = ((size_t)bh * 2048 + q0 + rl) * 64 + qd * 8;
  bf16x8 qh[2], qm[2], ql[2];
#pragma unroll
  for (int kk = 0; kk < 2; kk++) {
    qh[kk] = *(const bf16x8*)(Qb + qoff + kk * 32);
    qm[kk] = *(const bf16x8*)(Qb + 4194304 + qoff + kk * 32);
    ql[kk] = *(const bf16x8*)(Qb + 8388608 + qoff + kk * 32);
  }

  float mrun[4], lrun[4];
  f32x4 o[4];
#pragma unroll
  for (int r = 0; r < 4; r++) { mrun[r] = -1e30f; lrun[r] = 0.0f; }
#pragma unroll
  for (int jt = 0; jt < 4; jt++) o[jt] = f32x4{0.f, 0.f, 0.f, 0.f};

  for (int kv0 = 0; kv0 < 2048; kv0 += 128) {
    f32x4 sc[8];
#pragma unroll
    for (int nt = 0; nt < 8; nt++) sc[nt] = f32x4{0.f, 0.f, 0.f, 0.f};
#pragma unroll
    for (int nt = 0; nt < 8; nt++) {
      const size_t koff = ((size_t)bh * 2048 + kv0 + nt * 16 + rl) * 64 + qd * 8;
#pragma unroll
      for (int kk = 0; kk < 2; kk++) {
        bf16x8 kh = *(const bf16x8*)(Kb + koff + kk * 32);
        bf16x8 km = *(const bf16x8*)(Kb + 4194304 + koff + kk * 32);
        bf16x8 kl = *(const bf16x8*)(Kb + 8388608 + koff + kk * 32);
        f32x4 a = sc[nt];
        a = mfma_bf16(qh[kk], kh, a);
        a = mfma_bf16(qh[kk], km, a);
        a = mfma_bf16(qm[kk], kh, a);
        a = mfma_bf16(qm[kk], km, a);
        a = mfma_bf16(qh[kk], kl, a);
        a = mfma_bf16(ql[kk], kh, a);
        sc[nt] = a;
      }
    }
#pragma unroll
    for (int nt = 0; nt < 8; nt++)
#pragma unroll
      for (int r = 0; r < 4; r++) sc[nt][r] *= SCALE_LOG2E;

    float rmax[4];
#pragma unroll
    for (int r = 0; r < 4; r++) {
      float v = sc[0][r];
#pragma unroll
      for (int nt = 1; nt < 8; nt++) v = fmaxf(v, sc[nt][r]);
      rmax[r] = v;
    }
#pragma unroll
    for (int msk = 1; msk < 16; msk <<= 1)
#pragma unroll
      for (int r = 0; r < 4; r++)
        rmax[r] = fmaxf(rmax[r], __shfl_xor(rmax[r], msk, 64));

    float mnew[4], alpha[4], rsum[4];
#pragma unroll
    for (int r = 0; r < 4; r++) {
      mnew[r] = fmaxf(mrun[r], rmax[r]);
      alpha[r] = EXP2F(mrun[r] - mnew[r]);
      mrun[r] = mnew[r];
      rsum[r] = 0.0f;
    }
#pragma unroll
    for (int nt = 0; nt < 8; nt++)
#pragma unroll
      for (int r = 0; r < 4; r++) {
        float p = EXP2F(sc[nt][r] - mnew[r]);
        sc[nt][r] = p;
        rsum[r] += p;
      }
#pragma unroll
    for (int msk = 1; msk < 16; msk <<= 1)
#pragma unroll
      for (int r = 0; r < 4; r++) rsum[r] += __shfl_xor(rsum[r], msk, 64);
#pragma unroll
    for (int r = 0; r < 4; r++) lrun[r] = lrun[r] * alpha[r] + rsum[r];
#pragma unroll
    for (int jt = 0; jt < 4; jt++)
#pragma unroll
      for (int r = 0; r < 4; r++) o[jt][r] *= alpha[r];

    // P: C-layout -> LDS -> A-layout (m120-verified transform)
#pragma unroll
    for (int nt = 0; nt < 8; nt++)
#pragma unroll
      for (int r = 0; r < 4; r++)
        Pl[wv][qd * 4 + r][nt * 16 + rl] = f2bf(sc[nt][r]);

#pragma unroll
    for (int kk2 = 0; kk2 < 4; kk2++) {
      bf16x8 pf = *(const bf16x8*)&Pl[wv][rl][kk2 * 32 + qd * 8];
#pragma unroll
      for (int jt = 0; jt < 4; jt++) {
        bf16x8 vf = *(const bf16x8*)(Vt + ((size_t)bh * 64 + jt * 16 + rl) * 2048 + kv0 + kk2 * 32 + qd * 8);
        o[jt] = mfma_bf16(pf, vf, o[jt]);
      }
    }
  }

  const int b = bh >> 4, hh = bh & 15;
#pragma unroll
  for (int r = 0; r < 4; r++) {
    const float inv = 1.0f / lrun[r];
    const int s = q0 + qd * 4 + r;
#pragma unroll
    for (int jt = 0; jt < 4; jt++)
      Xo[((size_t)(b * 2048 + s)) * 1024 + hh * 64 + jt * 16 + rl] = f2bf(o[jt][r] * inv);
  }
}

// ---------------- output projection: plain bf16 GEMM -> fp32 out ----------------
__global__ __launch_bounds__(256) void gemm_out(
    const unsigned short* __restrict__ A0,
    const unsigned short* __restrict__ W0,
    const float* __restrict__ bias,
    float* __restrict__ out)
{
  __shared__ unsigned short LA[4096];
  __shared__ unsigned short LB[4096];
  const int tid = threadIdx.x;
  const int lane = tid & 63;
  const int wv = tid >> 6;
  const int wm = wv >> 1, wn = wv & 1;
  const int rl = lane & 15, qd = lane >> 4;
  const int m0 = blockIdx.y * 128, n0 = blockIdx.x * 128;

  f32x4 acc[4][4];
#pragma unroll
  for (int i = 0; i < 4; i++)
#pragma unroll
    for (int j = 0; j < 4; j++) acc[i][j] = f32x4{0.f, 0.f, 0.f, 0.f};

  const int srow = wv * 32 + (lane >> 2);
  const int scol = (lane & 3) * 8;

  for (int k0 = 0; k0 < 1024; k0 += 32) {
    const unsigned short* ga = A0 + (size_t)(m0 + srow) * 1024 + k0 + scol;
    async16(ga, &LA[wv * 1024]);
    async16(ga + 16 * 1024, &LA[wv * 1024 + 512]);
    const unsigned short* gb = W0 + (size_t)(n0 + srow) * 1024 + k0 + scol;
    async16(gb, &LB[wv * 1024]);
    async16(gb + 16 * 1024, &LB[wv * 1024 + 512]);
    __syncthreads();
    bf16x8 af[4], bfr[4];
#pragma unroll
    for (int i = 0; i < 4; i++) af[i] = *(const bf16x8*)&LA[(wm * 64 + i * 16 + rl) * 32 + qd * 8];
#pragma unroll
    for (int j = 0; j < 4; j++) bfr[j] = *(const bf16x8*)&LB[(wn * 64 + j * 16 + rl) * 32 + qd * 8];
#pragma unroll
    for (int i = 0; i < 4; i++)
#pragma unroll
      for (int j = 0; j < 4; j++) acc[i][j] = mfma_bf16(af[i], bfr[j], acc[i][j]);
    __syncthreads();
  }

#pragma unroll
  for (int j = 0; j < 4; j++) {
    const int nn = n0 + wn * 64 + j * 16 + rl;
    const float bj = bias[nn];
#pragma unroll
    for (int i = 0; i < 4; i++) {
      const int mm = m0 + wm * 64 + i * 16 + qd * 4;
#pragma unroll
      for (int r = 0; r < 4; r++)
        out[(size_t)(mm + r) * 1024 + nn] = acc[i][j][r] + bj;
    }
  }
}

// ---------------- launch ----------------
extern "C" void kernel_launch(void* const* d_in, const int* in_sizes, int n_in,
                              void* d_out, int out_size, void* d_ws, size_t ws_size,
                              hipStream_t stream) {
  const float* query = (const float*)d_in[0];
  const float* key   = (const float*)d_in[1];
  const float* value = (const float*)d_in[2];
  const float* Wq = (const float*)d_in[3];
  const float* bq = (const float*)d_in[4];
  const float* Wk = (const float*)d_in[5];
  const float* bk = (const float*)d_in[6];
  const float* Wv = (const float*)d_in[7];
  const float* bv = (const float*)d_in[8];
  const float* Wo = (const float*)d_in[9];
  const float* bo = (const float*)d_in[10];

  // workspace layout (ushort elements); total 71,303,168 el = 136 MB
  unsigned short* ws = (unsigned short*)d_ws;
  const size_t E8 = 4194304;                 // elements per [4096,1024] plane
  unsigned short* Xq = ws;                   // 3 planes (query split)
  unsigned short* Xk = ws + 3 * E8;          // 3 planes (key split)
  unsigned short* Wsp = ws + 6 * E8;         // Wq 3 planes, Wk 3 planes (1048576 each)
  unsigned short* Xv  = Wsp + 6 * 1048576;   // value bf16
  unsigned short* Wvb = Xv + E8;
  unsigned short* Wob = Wvb + 1048576;
  unsigned short* Qh  = Wob + 1048576;       // Q 3 planes [B,H,S,HD]
  unsigned short* Kh  = Qh + 3 * E8;         // K 3 planes
  unsigned short* Vt  = Kh + 3 * E8;         // V^T [B,H,HD,S]
  unsigned short* Xa  = Vt + E8;             // attention out bf16 [B,S,D]

  split3_kernel<<<4096, 256, 0, stream>>>(query, Xq, Xq + E8, Xq + 2 * E8, 1048576);
  split3_kernel<<<4096, 256, 0, stream>>>(key,   Xk, Xk + E8, Xk + 2 * E8, 1048576);
  split3_kernel<<<1024, 256, 0, stream>>>(Wq, Wsp, Wsp + 1048576, Wsp + 2 * 1048576, 262144);
  split3_kernel<<<1024, 256, 0, stream>>>(Wk, Wsp + 3 * 1048576, Wsp + 4 * 1048576, Wsp + 5 * 1048576, 262144);
  cvt_kernel<<<4096, 256, 0, stream>>>(value, Xv, 1048576);
  cvt_kernel<<<1024, 256, 0, stream>>>(Wv, Wvb, 262144);
  cvt_kernel<<<1024, 256, 0, stream>>>(Wo, Wob, 262144);

  gemm_qk<<<dim3(8, 32, 2), 256, 0, stream>>>(Xq, Wsp, bq, bk, Qh);
  gemm_v<<<dim3(8, 32), 256, 0, stream>>>(Xv, Wvb, bv, Vt);
  attn_kernel<<<dim3(32, 32), 256, 0, stream>>>(Qh, Kh, Vt, Xa);
  gemm_out<<<dim3(8, 32), 256, 0, stream>>>(Xa, Wob, bo, (float*)d_out);
}

// Round 2
// 387.247 us; speedup vs baseline: 1.9927x; 1.9927x over previous
//
#include <hip/hip_runtime.h>
#include <stdint.h>
#include <stddef.h>

// Problem constants (B=2,S=2048,D=1024,H=16,HD=64)
#define SCALE_LOG2E 11.541560327111707f   // 8 * log2(e): scores*8, softmax in exp2 domain
#define E8 4194304                        // 4096*1024 plane
#define M1 1048576                        // 1024*1024 plane

typedef __attribute__((ext_vector_type(8))) __bf16 bf16x8;
typedef __attribute__((ext_vector_type(4))) float f32x4;

#if __has_builtin(__builtin_amdgcn_exp2f)
#define EXP2F(x) __builtin_amdgcn_exp2f(x)
#else
#define EXP2F(x) exp2f(x)
#endif

__device__ __forceinline__ f32x4 mfma_bf16(bf16x8 a, bf16x8 b, f32x4 c) {
  return __builtin_amdgcn_mfma_f32_16x16x32_bf16(a, b, c, 0, 0, 0);
}

__device__ __forceinline__ unsigned short f2bf(float f) {
  unsigned int u = __builtin_bit_cast(unsigned int, f);
  u += 0x7fffu + ((u >> 16) & 1u);           // RNE
  return (unsigned short)(u >> 16);
}
__device__ __forceinline__ float bf2f(unsigned short b) {
  unsigned int u = ((unsigned int)b) << 16;
  return __builtin_bit_cast(float, u);
}

// async global->LDS, 16B per lane. LDS dest is wave-uniform base + lane*16.
__device__ __forceinline__ void async16(const void* g, void* lds) {
  __builtin_amdgcn_global_load_lds(
      (const __attribute__((address_space(1))) unsigned int*)g,
      (__attribute__((address_space(3))) unsigned int*)lds, 16, 0, 0);
}

// ---------------- conversion / splitting ----------------
// 2-way split: f = hi + mid (+ ~2^-17 rel residual) — sufficient for score path.
__global__ void split2_kernel(const float* __restrict__ src,
                              unsigned short* __restrict__ dh,
                              unsigned short* __restrict__ dm, int n4) {
  int i = blockIdx.x * blockDim.x + threadIdx.x;
  if (i >= n4) return;
  float4 v = ((const float4*)src)[i];
  float vv[4] = {v.x, v.y, v.z, v.w};
  unsigned short hs[4], ms[4];
#pragma unroll
  for (int c = 0; c < 4; c++) {
    float f = vv[c];
    unsigned short h = f2bf(f);
    float r1 = f - bf2f(h);           // exact
    hs[c] = h; ms[c] = f2bf(r1);
  }
  ((ushort4*)dh)[i] = make_ushort4(hs[0], hs[1], hs[2], hs[3]);
  ((ushort4*)dm)[i] = make_ushort4(ms[0], ms[1], ms[2], ms[3]);
}

__global__ void cvt_kernel(const float* __restrict__ src,
                           unsigned short* __restrict__ dst, int n4) {
  int i = blockIdx.x * blockDim.x + threadIdx.x;
  if (i >= n4) return;
  float4 v = ((const float4*)src)[i];
  ((ushort4*)dst)[i] = make_ushort4(f2bf(v.x), f2bf(v.y), f2bf(v.z), f2bf(v.w));
}

// ---------------- Q/K projection: 2-plane split GEMM (hh+hm+mh) ----------------
// z=0 -> Q (bias bq), z=1 -> K (bias bk). Output: 2 bf16 planes, [B,H,S,HD].
__global__ __launch_bounds__(256) void gemm_qk(
    const unsigned short* __restrict__ Xbase,   // z-stride 2*E8, plane stride E8
    const unsigned short* __restrict__ Wbase,   // z-stride 2*M1, plane stride M1
    const float* __restrict__ bq, const float* __restrict__ bk,
    unsigned short* __restrict__ Obase)         // z-stride 2*E8, plane stride E8
{
  __shared__ unsigned short LA[2][4096];
  __shared__ unsigned short LB[2][4096];
  const int z = blockIdx.z;
  const int tid = threadIdx.x;
  const int lane = tid & 63;
  const int wv = tid >> 6;
  const int wm = wv >> 1, wn = wv & 1;
  const int rl = lane & 15, qd = lane >> 4;
  const int m0 = blockIdx.y * 128, n0 = blockIdx.x * 128;

  const unsigned short* A0 = Xbase + (size_t)z * (2 * (size_t)E8);
  const unsigned short* W0 = Wbase + (size_t)z * (2 * (size_t)M1);
  const float* bias = z ? bk : bq;
  unsigned short* O0 = Obase + (size_t)z * (2 * (size_t)E8);

  f32x4 acc[4][4];
#pragma unroll
  for (int i = 0; i < 4; i++)
#pragma unroll
    for (int j = 0; j < 4; j++) acc[i][j] = f32x4{0.f, 0.f, 0.f, 0.f};

  const int srow = wv * 32 + (lane >> 2);
  const int scol = (lane & 3) * 8;

  for (int k0 = 0; k0 < 1024; k0 += 32) {
#pragma unroll
    for (int p = 0; p < 2; p++) {
      const unsigned short* ga = A0 + (size_t)p * E8 + (size_t)(m0 + srow) * 1024 + k0 + scol;
      async16(ga, &LA[p][wv * 1024]);
      async16(ga + 16 * 1024, &LA[p][wv * 1024 + 512]);
      const unsigned short* gb = W0 + (size_t)p * M1 + (size_t)(n0 + srow) * 1024 + k0 + scol;
      async16(gb, &LB[p][wv * 1024]);
      async16(gb + 16 * 1024, &LB[p][wv * 1024 + 512]);
    }
    __syncthreads();
    bf16x8 ah[4], am[4];
#pragma unroll
    for (int i = 0; i < 4; i++) {
      int ro = (wm * 64 + i * 16 + rl) * 32 + qd * 8;
      ah[i] = *(const bf16x8*)&LA[0][ro];
      am[i] = *(const bf16x8*)&LA[1][ro];
    }
#pragma unroll
    for (int j = 0; j < 4; j++) {
      int ro = (wn * 64 + j * 16 + rl) * 32 + qd * 8;
      bf16x8 bh = *(const bf16x8*)&LB[0][ro];
      bf16x8 bm = *(const bf16x8*)&LB[1][ro];
#pragma unroll
      for (int i = 0; i < 4; i++) {
        f32x4 a = acc[i][j];
        a = mfma_bf16(ah[i], bh, a);
        a = mfma_bf16(ah[i], bm, a);
        a = mfma_bf16(am[i], bh, a);
        acc[i][j] = a;
      }
    }
    __syncthreads();
  }

  // epilogue: +bias, 2-way split, heads layout [B,H,S,HD]
#pragma unroll
  for (int j = 0; j < 4; j++) {
    const int nn = n0 + wn * 64 + j * 16 + rl;
    const float bj = bias[nn];
    const int hh = nn >> 6, e = nn & 63;
#pragma unroll
    for (int i = 0; i < 4; i++) {
      const int mm = m0 + wm * 64 + i * 16 + qd * 4;
      const int b = mm >> 11;
#pragma unroll
      for (int r = 0; r < 4; r++) {
        const int s = (mm + r) & 2047;
        size_t idx = ((size_t)((b * 16 + hh) * 2048 + s) << 6) + e;
        float v = acc[i][j][r] + bj;
        unsigned short h = f2bf(v);
        float r1 = v - bf2f(h);
        O0[idx] = h;
        O0[idx + E8] = f2bf(r1);
      }
    }
  }
}

// ---------------- V projection: plain bf16 GEMM, writes V^T [B,H,HD,S] ----------------
__global__ __launch_bounds__(256) void gemm_v(
    const unsigned short* __restrict__ A0,
    const unsigned short* __restrict__ W0,
    const float* __restrict__ bias,
    unsigned short* __restrict__ Vt)
{
  __shared__ unsigned short LA[4096];
  __shared__ unsigned short LB[4096];
  const int tid = threadIdx.x;
  const int lane = tid & 63;
  const int wv = tid >> 6;
  const int wm = wv >> 1, wn = wv & 1;
  const int rl = lane & 15, qd = lane >> 4;
  const int m0 = blockIdx.y * 128, n0 = blockIdx.x * 128;

  f32x4 acc[4][4];
#pragma unroll
  for (int i = 0; i < 4; i++)
#pragma unroll
    for (int j = 0; j < 4; j++) acc[i][j] = f32x4{0.f, 0.f, 0.f, 0.f};

  const int srow = wv * 32 + (lane >> 2);
  const int scol = (lane & 3) * 8;

  for (int k0 = 0; k0 < 1024; k0 += 32) {
    const unsigned short* ga = A0 + (size_t)(m0 + srow) * 1024 + k0 + scol;
    async16(ga, &LA[wv * 1024]);
    async16(ga + 16 * 1024, &LA[wv * 1024 + 512]);
    const unsigned short* gb = W0 + (size_t)(n0 + srow) * 1024 + k0 + scol;
    async16(gb, &LB[wv * 1024]);
    async16(gb + 16 * 1024, &LB[wv * 1024 + 512]);
    __syncthreads();
    bf16x8 af[4], bfr[4];
#pragma unroll
    for (int i = 0; i < 4; i++) af[i] = *(const bf16x8*)&LA[(wm * 64 + i * 16 + rl) * 32 + qd * 8];
#pragma unroll
    for (int j = 0; j < 4; j++) bfr[j] = *(const bf16x8*)&LB[(wn * 64 + j * 16 + rl) * 32 + qd * 8];
#pragma unroll
    for (int i = 0; i < 4; i++)
#pragma unroll
      for (int j = 0; j < 4; j++) acc[i][j] = mfma_bf16(af[i], bfr[j], acc[i][j]);
    __syncthreads();
  }

#pragma unroll
  for (int j = 0; j < 4; j++) {
    const int nn = n0 + wn * 64 + j * 16 + rl;
    const float bj = bias[nn];
    const int hh = nn >> 6, e = nn & 63;
#pragma unroll
    for (int i = 0; i < 4; i++) {
      const int mm = m0 + wm * 64 + i * 16 + qd * 4;
      const int b = mm >> 11, s = mm & 2047;
      ushort4 pk = make_ushort4(f2bf(acc[i][j][0] + bj), f2bf(acc[i][j][1] + bj),
                                f2bf(acc[i][j][2] + bj), f2bf(acc[i][j][3] + bj));
      *(ushort4*)(Vt + (((size_t)((b * 16 + hh) * 64 + e)) << 11) + s) = pk;
    }
  }
}

// ---------------- flash attention v2 ----------------
// grid (32, 32): x = q-block (64 rows), y = bh. Block 128 threads (2 waves x 32 q-rows).
// K tiles (64 keys, hi+mid) staged in LDS via global_load_lds with xor-swizzled 16B
// chunks (conflict-free frag reads). V frags prefetched to registers per tile.
__global__ __launch_bounds__(128, 2) void attn_kernel(
    const unsigned short* __restrict__ Qb,   // 2 planes stride E8, [B,H,S,HD]
    const unsigned short* __restrict__ Kb,   // 2 planes
    const unsigned short* __restrict__ Vt,   // [B,H,HD,S]
    unsigned short* __restrict__ Xo)         // [B,S,D] bf16
{
  __shared__ unsigned short Ks[2][4096];     // [plane][64 keys x 64 d], 16B-chunk xor swizzle
  __shared__ unsigned short Ps[2][32][72];   // [wave][q row][key] pad 64->72
  const int tid = threadIdx.x;
  const int lane = tid & 63;
  const int wv = tid >> 6;
  const int rl = lane & 15, qd = lane >> 4;
  const int bh = blockIdx.y;
  const int q0 = blockIdx.x * 64 + wv * 32;

  // Q fragments: [plane][mtile][kk]
  bf16x8 qf[2][2][2];
#pragma unroll
  for (int mt = 0; mt < 2; mt++)
#pragma unroll
    for (int kk = 0; kk < 2; kk++) {
      const size_t off = ((size_t)bh * 2048 + q0 + mt * 16 + rl) * 64 + kk * 32 + qd * 8;
      qf[0][mt][kk] = *(const bf16x8*)(Qb + off);
      qf[1][mt][kk] = *(const bf16x8*)(Qb + E8 + off);
    }

  float m_[2][4], l_[2][4];
  f32x4 o[2][4];
#pragma unroll
  for (int mt = 0; mt < 2; mt++)
#pragma unroll
    for (int r = 0; r < 4; r++) { m_[mt][r] = -1e30f; l_[mt][r] = 0.0f; }
#pragma unroll
  for (int mt = 0; mt < 2; mt++)
#pragma unroll
    for (int jt = 0; jt < 4; jt++) o[mt][jt] = f32x4{0.f, 0.f, 0.f, 0.f};

  for (int kv0 = 0; kv0 < 2048; kv0 += 64) {
    // ---- stage K tile (2 planes x 8KB) via async DMA, xor-swizzled ----
#pragma unroll
    for (int p = 0; p < 2; p++)
#pragma unroll
      for (int j = 0; j < 4; j++) {
        const int cI = j * 128 + tid;            // 16B chunk index
        const int row = cI >> 3;
        const int c = (cI & 7) ^ (row & 7);      // source chunk (swizzle)
        const unsigned short* src = Kb + (size_t)p * E8 +
            ((size_t)bh * 2048 + kv0 + row) * 64 + c * 8;
        async16(src, &Ks[p][j * 1024 + wv * 512]);
      }
    __syncthreads();

    // ---- prefetch V fragments for this tile ----
    bf16x8 vf[2][4];
#pragma unroll
    for (int kk2 = 0; kk2 < 2; kk2++)
#pragma unroll
      for (int jt = 0; jt < 4; jt++)
        vf[kk2][jt] = *(const bf16x8*)(Vt + ((size_t)bh * 64 + jt * 16 + rl) * 2048 +
                                       kv0 + kk2 * 32 + qd * 8);

    // ---- QK^T: sc[mt][nt] ----
    f32x4 sc[2][4];
#pragma unroll
    for (int mt = 0; mt < 2; mt++)
#pragma unroll
      for (int nt = 0; nt < 4; nt++) sc[mt][nt] = f32x4{0.f, 0.f, 0.f, 0.f};
#pragma unroll
    for (int nt = 0; nt < 4; nt++)
#pragma unroll
      for (int kk = 0; kk < 2; kk++) {
        const int ro = (nt * 16 + rl) * 64 + (((kk * 4 + qd) ^ (rl & 7)) << 3);
        bf16x8 kh = *(const bf16x8*)&Ks[0][ro];
        bf16x8 km = *(const bf16x8*)&Ks[1][ro];
#pragma unroll
        for (int mt = 0; mt < 2; mt++) {
          f32x4 a = sc[mt][nt];
          a = mfma_bf16(qf[0][mt][kk], kh, a);
          a = mfma_bf16(qf[0][mt][kk], km, a);
          a = mfma_bf16(qf[1][mt][kk], kh, a);
          sc[mt][nt] = a;
        }
      }

    // ---- online softmax ----
#pragma unroll
    for (int mt = 0; mt < 2; mt++) {
      float rmax[4];
#pragma unroll
      for (int r = 0; r < 4; r++) {
        float v = sc[mt][0][r] * SCALE_LOG2E;
        sc[mt][0][r] = v;
#pragma unroll
        for (int nt = 1; nt < 4; nt++) {
          float w = sc[mt][nt][r] * SCALE_LOG2E;
          sc[mt][nt][r] = w;
          v = fmaxf(v, w);
        }
        rmax[r] = v;
      }
#pragma unroll
      for (int msk = 1; msk < 16; msk <<= 1)
#pragma unroll
        for (int r = 0; r < 4; r++)
          rmax[r] = fmaxf(rmax[r], __shfl_xor(rmax[r], msk, 64));

      float alpha[4], rsum[4];
#pragma unroll
      for (int r = 0; r < 4; r++) {
        float mnew = fmaxf(m_[mt][r], rmax[r]);
        alpha[r] = EXP2F(m_[mt][r] - mnew);
        m_[mt][r] = mnew;
        rsum[r] = 0.0f;
      }
#pragma unroll
      for (int nt = 0; nt < 4; nt++)
#pragma unroll
        for (int r = 0; r < 4; r++) {
          float p = EXP2F(sc[mt][nt][r] - m_[mt][r]);
          sc[mt][nt][r] = p;
          rsum[r] += p;
        }
#pragma unroll
      for (int msk = 1; msk < 16; msk <<= 1)
#pragma unroll
        for (int r = 0; r < 4; r++) rsum[r] += __shfl_xor(rsum[r], msk, 64);
#pragma unroll
      for (int r = 0; r < 4; r++) l_[mt][r] = l_[mt][r] * alpha[r] + rsum[r];
#pragma unroll
      for (int jt = 0; jt < 4; jt++)
#pragma unroll
        for (int r = 0; r < 4; r++) o[mt][jt][r] *= alpha[r];

      // P: C-layout -> LDS (per-wave region, no barrier)
#pragma unroll
      for (int nt = 0; nt < 4; nt++)
#pragma unroll
        for (int r = 0; r < 4; r++)
          Ps[wv][mt * 16 + qd * 4 + r][nt * 16 + rl] = f2bf(sc[mt][nt][r]);
    }

    // ---- PV ----
#pragma unroll
    for (int kk2 = 0; kk2 < 2; kk2++) {
      bf16x8 pf[2];
#pragma unroll
      for (int mt = 0; mt < 2; mt++)
        pf[mt] = *(const bf16x8*)&Ps[wv][mt * 16 + rl][kk2 * 32 + qd * 8];
#pragma unroll
      for (int jt = 0; jt < 4; jt++)
#pragma unroll
        for (int mt = 0; mt < 2; mt++)
          o[mt][jt] = mfma_bf16(pf[mt], vf[kk2][jt], o[mt][jt]);
    }
    __syncthreads();
  }

  const int b = bh >> 4, hh = bh & 15;
#pragma unroll
  for (int mt = 0; mt < 2; mt++)
#pragma unroll
    for (int r = 0; r < 4; r++) {
      const float inv = 1.0f / l_[mt][r];
      const int s = q0 + mt * 16 + qd * 4 + r;
#pragma unroll
      for (int jt = 0; jt < 4; jt++)
        Xo[((size_t)(b * 2048 + s)) * 1024 + hh * 64 + jt * 16 + rl] =
            f2bf(o[mt][jt][r] * inv);
    }
}

// ---------------- output projection: plain bf16 GEMM -> fp32 out ----------------
__global__ __launch_bounds__(256) void gemm_out(
    const unsigned short* __restrict__ A0,
    const unsigned short* __restrict__ W0,
    const float* __restrict__ bias,
    float* __restrict__ out)
{
  __shared__ unsigned short LA[4096];
  __shared__ unsigned short LB[4096];
  const int tid = threadIdx.x;
  const int lane = tid & 63;
  const int wv = tid >> 6;
  const int wm = wv >> 1, wn = wv & 1;
  const int rl = lane & 15, qd = lane >> 4;
  const int m0 = blockIdx.y * 128, n0 = blockIdx.x * 128;

  f32x4 acc[4][4];
#pragma unroll
  for (int i = 0; i < 4; i++)
#pragma unroll
    for (int j = 0; j < 4; j++) acc[i][j] = f32x4{0.f, 0.f, 0.f, 0.f};

  const int srow = wv * 32 + (lane >> 2);
  const int scol = (lane & 3) * 8;

  for (int k0 = 0; k0 < 1024; k0 += 32) {
    const unsigned short* ga = A0 + (size_t)(m0 + srow) * 1024 + k0 + scol;
    async16(ga, &LA[wv * 1024]);
    async16(ga + 16 * 1024, &LA[wv * 1024 + 512]);
    const unsigned short* gb = W0 + (size_t)(n0 + srow) * 1024 + k0 + scol;
    async16(gb, &LB[wv * 1024]);
    async16(gb + 16 * 1024, &LB[wv * 1024 + 512]);
    __syncthreads();
    bf16x8 af[4], bfr[4];
#pragma unroll
    for (int i = 0; i < 4; i++) af[i] = *(const bf16x8*)&LA[(wm * 64 + i * 16 + rl) * 32 + qd * 8];
#pragma unroll
    for (int j = 0; j < 4; j++) bfr[j] = *(const bf16x8*)&LB[(wn * 64 + j * 16 + rl) * 32 + qd * 8];
#pragma unroll
    for (int i = 0; i < 4; i++)
#pragma unroll
      for (int j = 0; j < 4; j++) acc[i][j] = mfma_bf16(af[i], bfr[j], acc[i][j]);
    __syncthreads();
  }

#pragma unroll
  for (int j = 0; j < 4; j++) {
    const int nn = n0 + wn * 64 + j * 16 + rl;
    const float bj = bias[nn];
#pragma unroll
    for (int i = 0; i < 4; i++) {
      const int mm = m0 + wm * 64 + i * 16 + qd * 4;
#pragma unroll
      for (int r = 0; r < 4; r++)
        out[(size_t)(mm + r) * 1024 + nn] = acc[i][j][r] + bj;
    }
  }
}

// ---------------- launch ----------------
extern "C" void kernel_launch(void* const* d_in, const int* in_sizes, int n_in,
                              void* d_out, int out_size, void* d_ws, size_t ws_size,
                              hipStream_t stream) {
  const float* query = (const float*)d_in[0];
  const float* key   = (const float*)d_in[1];
  const float* value = (const float*)d_in[2];
  const float* Wq = (const float*)d_in[3];
  const float* bq = (const float*)d_in[4];
  const float* Wk = (const float*)d_in[5];
  const float* bk = (const float*)d_in[6];
  const float* Wv = (const float*)d_in[7];
  const float* bv = (const float*)d_in[8];
  const float* Wo = (const float*)d_in[9];
  const float* bo = (const float*)d_in[10];

  // workspace layout (ushort elements); ~52.4M el = 105 MB
  unsigned short* ws = (unsigned short*)d_ws;
  unsigned short* Xqk = ws;                     // 4*E8: q hi,mid, k hi,mid
  unsigned short* Wqk = ws + 4 * (size_t)E8;    // 4*M1: Wq hi,mid, Wk hi,mid
  unsigned short* Xv  = Wqk + 4 * (size_t)M1;   // E8
  unsigned short* Wvb = Xv + (size_t)E8;        // M1
  unsigned short* Wob = Wvb + (size_t)M1;       // M1
  unsigned short* QKh = Wob + (size_t)M1;       // 4*E8: Q hi,mid, K hi,mid [B,H,S,HD]
  unsigned short* Vt  = QKh + 4 * (size_t)E8;   // E8  [B,H,HD,S]
  unsigned short* Xa  = Vt + (size_t)E8;        // E8  [B,S,D]

  split2_kernel<<<4096, 256, 0, stream>>>(query, Xqk, Xqk + E8, 1048576);
  split2_kernel<<<4096, 256, 0, stream>>>(key, Xqk + 2 * (size_t)E8, Xqk + 3 * (size_t)E8, 1048576);
  split2_kernel<<<1024, 256, 0, stream>>>(Wq, Wqk, Wqk + M1, 262144);
  split2_kernel<<<1024, 256, 0, stream>>>(Wk, Wqk + 2 * (size_t)M1, Wqk + 3 * (size_t)M1, 262144);
  cvt_kernel<<<4096, 256, 0, stream>>>(value, Xv, 1048576);
  cvt_kernel<<<1024, 256, 0, stream>>>(Wv, Wvb, 262144);
  cvt_kernel<<<1024, 256, 0, stream>>>(Wo, Wob, 262144);

  gemm_qk<<<dim3(8, 32, 2), 256, 0, stream>>>(Xqk, Wqk, bq, bk, QKh);
  gemm_v<<<dim3(8, 32), 256, 0, stream>>>(Xv, Wvb, bv, Vt);
  attn_kernel<<<dim3(32, 32), 128, 0, stream>>>(QKh, QKh + 2 * (size_t)E8, Vt, Xa);
  gemm_out<<<dim3(8, 32), 256, 0, stream>>>(Xa, Wob, bo, (float*)d_out);
}

// Round 3
// 338.951 us; speedup vs baseline: 2.2767x; 1.1425x over previous
//
#include <hip/hip_runtime.h>
#include <stdint.h>
#include <stddef.h>

// Problem constants (B=2,S=2048,D=1024,H=16,HD=64)
#define SCALE_LOG2E 11.541560327111707f   // 8 * log2(e): folded into Q projection
#define E8 4194304                        // 4096*1024 plane
#define M1 1048576                        // 1024*1024 plane

typedef __attribute__((ext_vector_type(8))) __bf16 bf16x8;
typedef __attribute__((ext_vector_type(4))) float f32x4;

#if __has_builtin(__builtin_amdgcn_exp2f)
#define EXP2F(x) __builtin_amdgcn_exp2f(x)
#else
#define EXP2F(x) exp2f(x)
#endif

__device__ __forceinline__ f32x4 mfma_bf16(bf16x8 a, bf16x8 b, f32x4 c) {
  return __builtin_amdgcn_mfma_f32_16x16x32_bf16(a, b, c, 0, 0, 0);
}

__device__ __forceinline__ unsigned short f2bf(float f) {
  unsigned int u = __builtin_bit_cast(unsigned int, f);
  u += 0x7fffu + ((u >> 16) & 1u);           // RNE
  return (unsigned short)(u >> 16);
}
__device__ __forceinline__ float bf2f(unsigned short b) {
  unsigned int u = ((unsigned int)b) << 16;
  return __builtin_bit_cast(float, u);
}

// async global->LDS, 16B per lane. LDS dest is wave-uniform base + lane*16.
__device__ __forceinline__ void async16(const void* g, void* lds) {
  __builtin_amdgcn_global_load_lds(
      (const __attribute__((address_space(1))) unsigned int*)g,
      (__attribute__((address_space(3))) unsigned int*)lds, 16, 0, 0);
}

// ---------------- merged conversion / splitting ----------------
// z=0: split query, z=1: split key, z=2: cvt value. n4 = 1048576 per segment.
__global__ void prep_big(const float* __restrict__ query,
                         const float* __restrict__ key,
                         const float* __restrict__ value,
                         unsigned short* __restrict__ qh, unsigned short* __restrict__ qm,
                         unsigned short* __restrict__ kh, unsigned short* __restrict__ km,
                         unsigned short* __restrict__ vb) {
  const int i = blockIdx.x * blockDim.x + threadIdx.x;
  const int z = blockIdx.y;
  const float* src = (z == 0) ? query : (z == 1) ? key : value;
  float4 v = ((const float4*)src)[i];
  float vv[4] = {v.x, v.y, v.z, v.w};
  if (z == 2) {
    ((ushort4*)vb)[i] = make_ushort4(f2bf(vv[0]), f2bf(vv[1]), f2bf(vv[2]), f2bf(vv[3]));
    return;
  }
  unsigned short hs[4], ms[4];
#pragma unroll
  for (int c = 0; c < 4; c++) {
    float f = vv[c];
    unsigned short h = f2bf(f);
    hs[c] = h; ms[c] = f2bf(f - bf2f(h));
  }
  unsigned short* dh = z ? kh : qh;
  unsigned short* dm = z ? km : qm;
  ((ushort4*)dh)[i] = make_ushort4(hs[0], hs[1], hs[2], hs[3]);
  ((ushort4*)dm)[i] = make_ushort4(ms[0], ms[1], ms[2], ms[3]);
}

// z=0: split Wq, z=1: split Wk, z=2: cvt Wv, z=3: cvt Wo. n4 = 262144 each.
__global__ void prep_w(const float* __restrict__ Wq, const float* __restrict__ Wk,
                       const float* __restrict__ Wv, const float* __restrict__ Wo,
                       unsigned short* __restrict__ wqh, unsigned short* __restrict__ wqm,
                       unsigned short* __restrict__ wkh, unsigned short* __restrict__ wkm,
                       unsigned short* __restrict__ wvb, unsigned short* __restrict__ wob) {
  const int i = blockIdx.x * blockDim.x + threadIdx.x;
  const int z = blockIdx.y;
  const float* src = (z == 0) ? Wq : (z == 1) ? Wk : (z == 2) ? Wv : Wo;
  float4 v = ((const float4*)src)[i];
  float vv[4] = {v.x, v.y, v.z, v.w};
  if (z >= 2) {
    unsigned short* d = (z == 2) ? wvb : wob;
    ((ushort4*)d)[i] = make_ushort4(f2bf(vv[0]), f2bf(vv[1]), f2bf(vv[2]), f2bf(vv[3]));
    return;
  }
  unsigned short hs[4], ms[4];
#pragma unroll
  for (int c = 0; c < 4; c++) {
    float f = vv[c];
    unsigned short h = f2bf(f);
    hs[c] = h; ms[c] = f2bf(f - bf2f(h));
  }
  unsigned short* dh = z ? wkh : wqh;
  unsigned short* dm = z ? wkm : wqm;
  ((ushort4*)dh)[i] = make_ushort4(hs[0], hs[1], hs[2], hs[3]);
  ((ushort4*)dm)[i] = make_ushort4(ms[0], ms[1], ms[2], ms[3]);
}

// ---------------- Q/K projection: 2-plane split GEMM (hh+hm+mh) ----------------
// z=0 -> Q (bias bq, scaled by SCALE_LOG2E), z=1 -> K (bias bk).
__global__ __launch_bounds__(256) void gemm_qk(
    const unsigned short* __restrict__ Xbase,
    const unsigned short* __restrict__ Wbase,
    const float* __restrict__ bq, const float* __restrict__ bk,
    unsigned short* __restrict__ Obase)
{
  __shared__ unsigned short LA[2][4096];
  __shared__ unsigned short LB[2][4096];
  const int z = blockIdx.z;
  const int tid = threadIdx.x;
  const int lane = tid & 63;
  const int wv = tid >> 6;
  const int wm = wv >> 1, wn = wv & 1;
  const int rl = lane & 15, qd = lane >> 4;
  const int m0 = blockIdx.y * 128, n0 = blockIdx.x * 128;

  const unsigned short* A0 = Xbase + (size_t)z * (2 * (size_t)E8);
  const unsigned short* W0 = Wbase + (size_t)z * (2 * (size_t)M1);
  const float* bias = z ? bk : bq;
  const float scl = z ? 1.0f : SCALE_LOG2E;
  unsigned short* O0 = Obase + (size_t)z * (2 * (size_t)E8);

  f32x4 acc[4][4];
#pragma unroll
  for (int i = 0; i < 4; i++)
#pragma unroll
    for (int j = 0; j < 4; j++) acc[i][j] = f32x4{0.f, 0.f, 0.f, 0.f};

  const int srow = wv * 32 + (lane >> 2);
  const int scol = (lane & 3) * 8;

  for (int k0 = 0; k0 < 1024; k0 += 32) {
#pragma unroll
    for (int p = 0; p < 2; p++) {
      const unsigned short* ga = A0 + (size_t)p * E8 + (size_t)(m0 + srow) * 1024 + k0 + scol;
      async16(ga, &LA[p][wv * 1024]);
      async16(ga + 16 * 1024, &LA[p][wv * 1024 + 512]);
      const unsigned short* gb = W0 + (size_t)p * M1 + (size_t)(n0 + srow) * 1024 + k0 + scol;
      async16(gb, &LB[p][wv * 1024]);
      async16(gb + 16 * 1024, &LB[p][wv * 1024 + 512]);
    }
    __syncthreads();
    bf16x8 ah[4], am[4];
#pragma unroll
    for (int i = 0; i < 4; i++) {
      int ro = (wm * 64 + i * 16 + rl) * 32 + qd * 8;
      ah[i] = *(const bf16x8*)&LA[0][ro];
      am[i] = *(const bf16x8*)&LA[1][ro];
    }
#pragma unroll
    for (int j = 0; j < 4; j++) {
      int ro = (wn * 64 + j * 16 + rl) * 32 + qd * 8;
      bf16x8 bh = *(const bf16x8*)&LB[0][ro];
      bf16x8 bm = *(const bf16x8*)&LB[1][ro];
#pragma unroll
      for (int i = 0; i < 4; i++) {
        f32x4 a = acc[i][j];
        a = mfma_bf16(ah[i], bh, a);
        a = mfma_bf16(ah[i], bm, a);
        a = mfma_bf16(am[i], bh, a);
        acc[i][j] = a;
      }
    }
    __syncthreads();
  }

#pragma unroll
  for (int j = 0; j < 4; j++) {
    const int nn = n0 + wn * 64 + j * 16 + rl;
    const float bj = bias[nn];
    const int hh = nn >> 6, e = nn & 63;
#pragma unroll
    for (int i = 0; i < 4; i++) {
      const int mm = m0 + wm * 64 + i * 16 + qd * 4;
      const int b = mm >> 11;
#pragma unroll
      for (int r = 0; r < 4; r++) {
        const int s = (mm + r) & 2047;
        size_t idx = ((size_t)((b * 16 + hh) * 2048 + s) << 6) + e;
        float v = (acc[i][j][r] + bj) * scl;
        unsigned short h = f2bf(v);
        O0[idx] = h;
        O0[idx + E8] = f2bf(v - bf2f(h));
      }
    }
  }
}

// ---------------- V projection: plain bf16 GEMM, writes V^T [B,H,HD,S] ----------------
__global__ __launch_bounds__(256) void gemm_v(
    const unsigned short* __restrict__ A0,
    const unsigned short* __restrict__ W0,
    const float* __restrict__ bias,
    unsigned short* __restrict__ Vt)
{
  __shared__ unsigned short LA[4096];
  __shared__ unsigned short LB[4096];
  const int tid = threadIdx.x;
  const int lane = tid & 63;
  const int wv = tid >> 6;
  const int wm = wv >> 1, wn = wv & 1;
  const int rl = lane & 15, qd = lane >> 4;
  const int m0 = blockIdx.y * 128, n0 = blockIdx.x * 128;

  f32x4 acc[4][4];
#pragma unroll
  for (int i = 0; i < 4; i++)
#pragma unroll
    for (int j = 0; j < 4; j++) acc[i][j] = f32x4{0.f, 0.f, 0.f, 0.f};

  const int srow = wv * 32 + (lane >> 2);
  const int scol = (lane & 3) * 8;

  for (int k0 = 0; k0 < 1024; k0 += 32) {
    const unsigned short* ga = A0 + (size_t)(m0 + srow) * 1024 + k0 + scol;
    async16(ga, &LA[wv * 1024]);
    async16(ga + 16 * 1024, &LA[wv * 1024 + 512]);
    const unsigned short* gb = W0 + (size_t)(n0 + srow) * 1024 + k0 + scol;
    async16(gb, &LB[wv * 1024]);
    async16(gb + 16 * 1024, &LB[wv * 1024 + 512]);
    __syncthreads();
    bf16x8 af[4], bfr[4];
#pragma unroll
    for (int i = 0; i < 4; i++) af[i] = *(const bf16x8*)&LA[(wm * 64 + i * 16 + rl) * 32 + qd * 8];
#pragma unroll
    for (int j = 0; j < 4; j++) bfr[j] = *(const bf16x8*)&LB[(wn * 64 + j * 16 + rl) * 32 + qd * 8];
#pragma unroll
    for (int i = 0; i < 4; i++)
#pragma unroll
      for (int j = 0; j < 4; j++) acc[i][j] = mfma_bf16(af[i], bfr[j], acc[i][j]);
    __syncthreads();
  }

#pragma unroll
  for (int j = 0; j < 4; j++) {
    const int nn = n0 + wn * 64 + j * 16 + rl;
    const float bj = bias[nn];
    const int hh = nn >> 6, e = nn & 63;
#pragma unroll
    for (int i = 0; i < 4; i++) {
      const int mm = m0 + wm * 64 + i * 16 + qd * 4;
      const int b = mm >> 11, s = mm & 2047;
      ushort4 pk = make_ushort4(f2bf(acc[i][j][0] + bj), f2bf(acc[i][j][1] + bj),
                                f2bf(acc[i][j][2] + bj), f2bf(acc[i][j][3] + bj));
      *(ushort4*)(Vt + (((size_t)((b * 16 + hh) * 64 + e)) << 11) + s) = pk;
    }
  }
}

// ---------------- flash attention v3: S^T orientation ----------------
// grid (32, 32): x = q-block (64 rows), y = bh. Block 128 (2 waves x 32 q).
// S^T = K·Q^T  (A=K from LDS, B=Q regs)  -> softmax mostly in-lane (2 shuffles)
// O^T = V^T·P^T (A=V^T from global/L2, B=P^T via per-wave LDS round trip)
__global__ __launch_bounds__(128, 2) void attn_kernel(
    const unsigned short* __restrict__ Qb,   // 2 planes stride E8, [B,H,S,HD], pre-scaled
    const unsigned short* __restrict__ Kb,   // 2 planes
    const unsigned short* __restrict__ Vt,   // [B,H,HD,S]
    unsigned short* __restrict__ Xo)         // [B,S,D] bf16
{
  __shared__ unsigned short Ks[2][4096];     // [plane][64 keys x 64 d], xor-swizzled 16B chunks
  __shared__ unsigned short Ps[2][32][76];   // [wave][q][key] pitch 76 (152 B)
  const int tid = threadIdx.x;
  const int lane = tid & 63;
  const int wv = tid >> 6;
  const int rl = lane & 15, qd = lane >> 4;
  const int bh = blockIdx.y;
  const int q0 = blockIdx.x * 64 + wv * 32;

  // Q as B-operand fragments [plane][mt][kk]
  bf16x8 qf[2][2][2];
#pragma unroll
  for (int mt = 0; mt < 2; mt++)
#pragma unroll
    for (int kk = 0; kk < 2; kk++) {
      const size_t off = ((size_t)bh * 2048 + q0 + mt * 16 + rl) * 64 + kk * 32 + qd * 8;
      qf[0][mt][kk] = *(const bf16x8*)(Qb + off);
      qf[1][mt][kk] = *(const bf16x8*)(Qb + E8 + off);
    }

  float m_[2] = {-1e30f, -1e30f}, l_[2] = {0.f, 0.f};
  f32x4 o[2][4];
#pragma unroll
  for (int mt = 0; mt < 2; mt++)
#pragma unroll
    for (int jt = 0; jt < 4; jt++) o[mt][jt] = f32x4{0.f, 0.f, 0.f, 0.f};

  // stage K tile (2 planes x 8 KB) via async DMA, xor-swizzled 16B chunks
  auto stage = [&](int kv) {
#pragma unroll
    for (int p = 0; p < 2; p++)
#pragma unroll
      for (int it = 0; it < 4; it++) {
        const int cI = it * 128 + tid;         // chunk index 0..511
        const int row = cI >> 3;
        const int c = (cI & 7) ^ (row & 7);
        const unsigned short* src = Kb + (size_t)p * E8 +
            ((size_t)bh * 2048 + kv + row) * 64 + c * 8;
        async16(src, &Ks[p][(it * 128 + wv * 64) * 8]);
      }
  };

  stage(0);

  for (int kv0 = 0; kv0 < 2048; kv0 += 64) {
    __syncthreads();                           // Ks(t) ready (drains DMA)

    // prefetch V^T A-fragments from global (L2-resident), used in PV
    bf16x8 vfr[4][2];
#pragma unroll
    for (int jt = 0; jt < 4; jt++)
#pragma unroll
      for (int kk2 = 0; kk2 < 2; kk2++)
        vfr[jt][kk2] = *(const bf16x8*)(Vt + ((size_t)bh * 64 + jt * 16 + rl) * 2048 +
                                        kv0 + kk2 * 32 + qd * 8);

    // ---- QK^T (S^T): sc[mt][nt], key = 16nt + qd*4 + r, q = mt*16 + rl ----
    f32x4 sc[2][4];
#pragma unroll
    for (int mt = 0; mt < 2; mt++)
#pragma unroll
      for (int nt = 0; nt < 4; nt++) sc[mt][nt] = f32x4{0.f, 0.f, 0.f, 0.f};
#pragma unroll
    for (int nt = 0; nt < 4; nt++) {
      const int ro = (nt * 16 + rl) * 64;
#pragma unroll
      for (int kk = 0; kk < 2; kk++) {
        const int cc = (((kk * 4 + qd) ^ (rl & 7)) << 3);
        bf16x8 kh = *(const bf16x8*)&Ks[0][ro + cc];
        bf16x8 km = *(const bf16x8*)&Ks[1][ro + cc];
#pragma unroll
        for (int mt = 0; mt < 2; mt++) {
          f32x4 a = sc[mt][nt];
          a = mfma_bf16(kh, qf[0][mt][kk], a);
          a = mfma_bf16(km, qf[0][mt][kk], a);
          a = mfma_bf16(kh, qf[1][mt][kk], a);
          sc[mt][nt] = a;
        }
      }
    }

    __syncthreads();                           // all waves done reading Ks(t)
    if (kv0 + 64 < 2048) stage(kv0 + 64);      // DMA(t+1) overlaps softmax+PV

    // ---- online softmax (scores already in exp2 domain) ----
#pragma unroll
    for (int mt = 0; mt < 2; mt++) {
      float mx = sc[mt][0][0];
#pragma unroll
      for (int nt = 0; nt < 4; nt++)
#pragma unroll
        for (int r = 0; r < 4; r++) mx = fmaxf(mx, sc[mt][nt][r]);
      mx = fmaxf(mx, __shfl_xor(mx, 16));
      mx = fmaxf(mx, __shfl_xor(mx, 32));
      const float mnew = fmaxf(m_[mt], mx);
      const float al = EXP2F(m_[mt] - mnew);
      m_[mt] = mnew;
      float sm = 0.f;
#pragma unroll
      for (int nt = 0; nt < 4; nt++)
#pragma unroll
        for (int r = 0; r < 4; r++) {
          float p = EXP2F(sc[mt][nt][r] - mnew);
          sc[mt][nt][r] = p;
          sm += p;
        }
      sm += __shfl_xor(sm, 16);
      sm += __shfl_xor(sm, 32);
      l_[mt] = l_[mt] * al + sm;
#pragma unroll
      for (int jt = 0; jt < 4; jt++)
#pragma unroll
        for (int r = 0; r < 4; r++) o[mt][jt][r] *= al;

      // P^T (C-layout) -> Ps[q][key]: 4 contiguous keys per reg-group, b64 writes
#pragma unroll
      for (int nt = 0; nt < 4; nt++) {
        ushort4 pk = make_ushort4(f2bf(sc[mt][nt][0]), f2bf(sc[mt][nt][1]),
                                  f2bf(sc[mt][nt][2]), f2bf(sc[mt][nt][3]));
        *(ushort4*)&Ps[wv][mt * 16 + rl][nt * 16 + qd * 4] = pk;
      }
    }

    // ---- PV: O^T += V^T · P^T (per-wave Ps, no barrier) ----
#pragma unroll
    for (int kk2 = 0; kk2 < 2; kk2++) {
      bf16x8 pf[2];
#pragma unroll
      for (int mt = 0; mt < 2; mt++)
        pf[mt] = *(const bf16x8*)&Ps[wv][mt * 16 + rl][kk2 * 32 + qd * 8];
#pragma unroll
      for (int jt = 0; jt < 4; jt++)
#pragma unroll
        for (int mt = 0; mt < 2; mt++)
          o[mt][jt] = mfma_bf16(vfr[jt][kk2], pf[mt], o[mt][jt]);
    }
  }

  // epilogue: O^T -> Xo[B,S,D]; lane holds d = jt*16 + qd*4 + r for q = mt*16+rl
  const int b = bh >> 4, hh = bh & 15;
#pragma unroll
  for (int mt = 0; mt < 2; mt++) {
    const float inv = 1.0f / l_[mt];
    const int q = q0 + mt * 16 + rl;
#pragma unroll
    for (int jt = 0; jt < 4; jt++) {
      ushort4 pk = make_ushort4(f2bf(o[mt][jt][0] * inv), f2bf(o[mt][jt][1] * inv),
                                f2bf(o[mt][jt][2] * inv), f2bf(o[mt][jt][3] * inv));
      *(ushort4*)(Xo + ((size_t)(b * 2048 + q)) * 1024 + hh * 64 + jt * 16 + qd * 4) = pk;
    }
  }
}

// ---------------- output projection: plain bf16 GEMM -> fp32 out ----------------
__global__ __launch_bounds__(256) void gemm_out(
    const unsigned short* __restrict__ A0,
    const unsigned short* __restrict__ W0,
    const float* __restrict__ bias,
    float* __restrict__ out)
{
  __shared__ unsigned short LA[4096];
  __shared__ unsigned short LB[4096];
  const int tid = threadIdx.x;
  const int lane = tid & 63;
  const int wv = tid >> 6;
  const int wm = wv >> 1, wn = wv & 1;
  const int rl = lane & 15, qd = lane >> 4;
  const int m0 = blockIdx.y * 128, n0 = blockIdx.x * 128;

  f32x4 acc[4][4];
#pragma unroll
  for (int i = 0; i < 4; i++)
#pragma unroll
    for (int j = 0; j < 4; j++) acc[i][j] = f32x4{0.f, 0.f, 0.f, 0.f};

  const int srow = wv * 32 + (lane >> 2);
  const int scol = (lane & 3) * 8;

  for (int k0 = 0; k0 < 1024; k0 += 32) {
    const unsigned short* ga = A0 + (size_t)(m0 + srow) * 1024 + k0 + scol;
    async16(ga, &LA[wv * 1024]);
    async16(ga + 16 * 1024, &LA[wv * 1024 + 512]);
    const unsigned short* gb = W0 + (size_t)(n0 + srow) * 1024 + k0 + scol;
    async16(gb, &LB[wv * 1024]);
    async16(gb + 16 * 1024, &LB[wv * 1024 + 512]);
    __syncthreads();
    bf16x8 af[4], bfr[4];
#pragma unroll
    for (int i = 0; i < 4; i++) af[i] = *(const bf16x8*)&LA[(wm * 64 + i * 16 + rl) * 32 + qd * 8];
#pragma unroll
    for (int j = 0; j < 4; j++) bfr[j] = *(const bf16x8*)&LB[(wn * 64 + j * 16 + rl) * 32 + qd * 8];
#pragma unroll
    for (int i = 0; i < 4; i++)
#pragma unroll
      for (int j = 0; j < 4; j++) acc[i][j] = mfma_bf16(af[i], bfr[j], acc[i][j]);
    __syncthreads();
  }

#pragma unroll
  for (int j = 0; j < 4; j++) {
    const int nn = n0 + wn * 64 + j * 16 + rl;
    const float bj = bias[nn];
#pragma unroll
    for (int i = 0; i < 4; i++) {
      const int mm = m0 + wm * 64 + i * 16 + qd * 4;
#pragma unroll
      for (int r = 0; r < 4; r++)
        out[(size_t)(mm + r) * 1024 + nn] = acc[i][j][r] + bj;
    }
  }
}

// ---------------- launch ----------------
extern "C" void kernel_launch(void* const* d_in, const int* in_sizes, int n_in,
                              void* d_out, int out_size, void* d_ws, size_t ws_size,
                              hipStream_t stream) {
  const float* query = (const float*)d_in[0];
  const float* key   = (const float*)d_in[1];
  const float* value = (const float*)d_in[2];
  const float* Wq = (const float*)d_in[3];
  const float* bq = (const float*)d_in[4];
  const float* Wk = (const float*)d_in[5];
  const float* bk = (const float*)d_in[6];
  const float* Wv = (const float*)d_in[7];
  const float* bv = (const float*)d_in[8];
  const float* Wo = (const float*)d_in[9];
  const float* bo = (const float*)d_in[10];

  // workspace layout (ushort elements); ~52.4M el = 105 MB
  unsigned short* ws = (unsigned short*)d_ws;
  unsigned short* Xqk = ws;                     // 4*E8: q hi,mid, k hi,mid
  unsigned short* Wqk = ws + 4 * (size_t)E8;    // 4*M1: Wq hi,mid, Wk hi,mid
  unsigned short* Xv  = Wqk + 4 * (size_t)M1;   // E8
  unsigned short* Wvb = Xv + (size_t)E8;        // M1
  unsigned short* Wob = Wvb + (size_t)M1;       // M1
  unsigned short* QKh = Wob + (size_t)M1;       // 4*E8: Q hi,mid, K hi,mid [B,H,S,HD]
  unsigned short* Vt  = QKh + 4 * (size_t)E8;   // E8  [B,H,HD,S]
  unsigned short* Xa  = Vt + (size_t)E8;        // E8  [B,S,D]

  prep_big<<<dim3(4096, 3), 256, 0, stream>>>(query, key, value,
      Xqk, Xqk + (size_t)E8, Xqk + 2 * (size_t)E8, Xqk + 3 * (size_t)E8, Xv);
  prep_w<<<dim3(1024, 4), 256, 0, stream>>>(Wq, Wk, Wv, Wo,
      Wqk, Wqk + (size_t)M1, Wqk + 2 * (size_t)M1, Wqk + 3 * (size_t)M1, Wvb, Wob);

  gemm_qk<<<dim3(8, 32, 2), 256, 0, stream>>>(Xqk, Wqk, bq, bk, QKh);
  gemm_v<<<dim3(8, 32), 256, 0, stream>>>(Xv, Wvb, bv, Vt);
  attn_kernel<<<dim3(32, 32), 128, 0, stream>>>(QKh, QKh + 2 * (size_t)E8, Vt, Xa);
  gemm_out<<<dim3(8, 32), 256, 0, stream>>>(Xa, Wob, bo, (float*)d_out);
}

// Round 4
// 259.716 us; speedup vs baseline: 2.9712x; 1.3051x over previous
//
#include <hip/hip_runtime.h>
#include <stdint.h>
#include <stddef.h>

// Problem constants (B=2,S=2048,D=1024,H=16,HD=64)
#define SCALE_LOG2E 11.541560327111707f   // 8 * log2(e): folded into Q projection
#define E8 4194304                        // 4096*1024 plane (elements)
#define M1 1048576                        // 1024*1024 plane

typedef __attribute__((ext_vector_type(8))) _Float16 f16x8;
typedef __attribute__((ext_vector_type(4))) _Float16 f16x4;
typedef __attribute__((ext_vector_type(4))) float f32x4;

#if __has_builtin(__builtin_amdgcn_exp2f)
#define EXP2F(x) __builtin_amdgcn_exp2f(x)
#else
#define EXP2F(x) exp2f(x)
#endif

__device__ __forceinline__ f32x4 mfma_f16(f16x8 a, f16x8 b, f32x4 c) {
  return __builtin_amdgcn_mfma_f32_16x16x32_f16(a, b, c, 0, 0, 0);
}

// async global->LDS, 16B per lane. LDS dest is wave-uniform base + lane*16.
__device__ __forceinline__ void async16(const void* g, void* lds) {
  __builtin_amdgcn_global_load_lds(
      (const __attribute__((address_space(1))) unsigned int*)g,
      (__attribute__((address_space(3))) unsigned int*)lds, 16, 0, 0);
}

// ---------------- fp32 -> fp16 conversion ----------------
__global__ void prep_x(const float* __restrict__ q, const float* __restrict__ k,
                       const float* __restrict__ v, _Float16* __restrict__ dst) {
  const int i = blockIdx.x * 256 + threadIdx.x;   // 4096*256 = 1048576 float4 exactly
  const int z = blockIdx.y;
  const float* s = (z == 0) ? q : (z == 1) ? k : v;
  float4 x = ((const float4*)s)[i];
  f16x4 h = {(_Float16)x.x, (_Float16)x.y, (_Float16)x.z, (_Float16)x.w};
  ((f16x4*)(dst + (size_t)z * E8))[i] = h;
}

__global__ void prep_w4(const float* __restrict__ wq, const float* __restrict__ wk,
                        const float* __restrict__ wv, const float* __restrict__ wo,
                        _Float16* __restrict__ dst) {
  const int i = blockIdx.x * 256 + threadIdx.x;   // 1024*256 = 262144 float4 exactly
  const int z = blockIdx.y;
  const float* s = (z == 0) ? wq : (z == 1) ? wk : (z == 2) ? wv : wo;
  float4 x = ((const float4*)s)[i];
  f16x4 h = {(_Float16)x.x, (_Float16)x.y, (_Float16)x.z, (_Float16)x.w};
  ((f16x4*)(dst + (size_t)z * M1))[i] = h;
}

// ---------------- merged Q/K/V projection: plain fp16 GEMM ----------------
// z=0: Q (bias bq, *SCALE_LOG2E) -> [B,H,S,HD] at Of
// z=1: K (bias bk)               -> [B,H,S,HD] at Of+E8
// z=2: V (bias bv)               -> V^T [B,H,HD,S] at Of+2*E8
__global__ __launch_bounds__(256) void gemm_qkv(
    const _Float16* __restrict__ Xf,    // 3 planes stride E8: query,key,value fp16
    const _Float16* __restrict__ Wf,    // 4 planes stride M1: Wq,Wk,Wv,Wo fp16
    const float* __restrict__ bq, const float* __restrict__ bk,
    const float* __restrict__ bv,
    _Float16* __restrict__ Of)
{
  __shared__ _Float16 LA[4096];
  __shared__ _Float16 LB[4096];
  const int z = blockIdx.z;
  const int tid = threadIdx.x;
  const int lane = tid & 63;
  const int wv = tid >> 6;
  const int wm = wv >> 1, wn = wv & 1;
  const int rl = lane & 15, qd = lane >> 4;
  const int m0 = blockIdx.y * 128, n0 = blockIdx.x * 128;

  const _Float16* A0 = Xf + (size_t)z * E8;
  const _Float16* W0 = Wf + (size_t)z * M1;
  const float* bias = (z == 0) ? bq : (z == 1) ? bk : bv;

  f32x4 acc[4][4];
#pragma unroll
  for (int i = 0; i < 4; i++)
#pragma unroll
    for (int j = 0; j < 4; j++) acc[i][j] = f32x4{0.f, 0.f, 0.f, 0.f};

  const int srow = wv * 32 + (lane >> 2);
  const int scol = (lane & 3) * 8;

  for (int k0 = 0; k0 < 1024; k0 += 32) {
    const _Float16* ga = A0 + (size_t)(m0 + srow) * 1024 + k0 + scol;
    async16(ga, &LA[wv * 1024]);
    async16(ga + 16 * 1024, &LA[wv * 1024 + 512]);
    const _Float16* gb = W0 + (size_t)(n0 + srow) * 1024 + k0 + scol;
    async16(gb, &LB[wv * 1024]);
    async16(gb + 16 * 1024, &LB[wv * 1024 + 512]);
    __syncthreads();
    f16x8 af[4], bfr[4];
#pragma unroll
    for (int i = 0; i < 4; i++) af[i] = *(const f16x8*)&LA[(wm * 64 + i * 16 + rl) * 32 + qd * 8];
#pragma unroll
    for (int j = 0; j < 4; j++) bfr[j] = *(const f16x8*)&LB[(wn * 64 + j * 16 + rl) * 32 + qd * 8];
#pragma unroll
    for (int i = 0; i < 4; i++)
#pragma unroll
      for (int j = 0; j < 4; j++) acc[i][j] = mfma_f16(af[i], bfr[j], acc[i][j]);
    __syncthreads();
  }

  if (z == 2) {
    // V^T epilogue: Vt[b,h,e,s], 4 contiguous s per store
#pragma unroll
    for (int j = 0; j < 4; j++) {
      const int nn = n0 + wn * 64 + j * 16 + rl;
      const float bj = bias[nn];
      const int hh = nn >> 6, e = nn & 63;
#pragma unroll
      for (int i = 0; i < 4; i++) {
        const int mm = m0 + wm * 64 + i * 16 + qd * 4;
        const int b = mm >> 11, s = mm & 2047;
        f16x4 pk = {(_Float16)(acc[i][j][0] + bj), (_Float16)(acc[i][j][1] + bj),
                    (_Float16)(acc[i][j][2] + bj), (_Float16)(acc[i][j][3] + bj)};
        *(f16x4*)(Of + 2 * (size_t)E8 + (((size_t)((b * 16 + hh) * 64 + e)) << 11) + s) = pk;
      }
    }
  } else {
    const float scl = (z == 0) ? SCALE_LOG2E : 1.0f;
    _Float16* base = Of + (size_t)z * E8;
#pragma unroll
    for (int j = 0; j < 4; j++) {
      const int nn = n0 + wn * 64 + j * 16 + rl;
      const float bj = bias[nn];
      const int hh = nn >> 6, e = nn & 63;
#pragma unroll
      for (int i = 0; i < 4; i++) {
        const int mm = m0 + wm * 64 + i * 16 + qd * 4;
        const int b = mm >> 11;
#pragma unroll
        for (int r = 0; r < 4; r++) {
          const int s = (mm + r) & 2047;
          base[((size_t)((b * 16 + hh) * 2048 + s) << 6) + e] =
              (_Float16)((acc[i][j][r] + bj) * scl);
        }
      }
    }
  }
}

// ---------------- flash attention v4: fp16, K+V double-buffered DMA ----------------
// grid (16, 32): x = q-block (128 rows), y = bh. Block 256 (4 waves x 32 q).
// S^T = K·Q^T; O^T = V^T·P^T. One barrier per KV tile; DMA(t+1) in flight
// during compute(t). o-rescale skipped when running max unchanged (wave ballot).
__global__ __launch_bounds__(256, 2) void attn_kernel(
    const _Float16* __restrict__ Qb,   // [B,H,S,HD], pre-scaled by 8*log2e
    const _Float16* __restrict__ Kb,   // [B,H,S,HD]
    const _Float16* __restrict__ Vt,   // [B,H,HD,S]
    _Float16* __restrict__ Xo)         // [B,S,D] fp16
{
  __shared__ _Float16 Ks[2][4096];     // dbuf [64 keys][64 d], xor-swizzled 16B chunks
  __shared__ _Float16 Vs[2][4096];     // dbuf [64 d][64 keys], same swizzle
  __shared__ _Float16 Ps[4][32][76];   // [wave][q][key], pitch 76 (0-conflict in R3)
  const int tid = threadIdx.x;
  const int lane = tid & 63;
  const int wv = tid >> 6;
  const int rl = lane & 15, qd = lane >> 4;
  const int bh = blockIdx.y;
  const int q0 = blockIdx.x * 128 + wv * 32;

  // Q as B-operand fragments [mt][kk]
  f16x8 qf[2][2];
#pragma unroll
  for (int mt = 0; mt < 2; mt++)
#pragma unroll
    for (int kk = 0; kk < 2; kk++)
      qf[mt][kk] = *(const f16x8*)(Qb + ((size_t)bh * 2048 + q0 + mt * 16 + rl) * 64 +
                                   kk * 32 + qd * 8);

  float m_[2] = {-1e30f, -1e30f}, l_[2] = {0.f, 0.f};
  f32x4 o[2][4];
#pragma unroll
  for (int mt = 0; mt < 2; mt++)
#pragma unroll
    for (int jt = 0; jt < 4; jt++) o[mt][jt] = f32x4{0.f, 0.f, 0.f, 0.f};

  // stage K and V tiles (8 KB each) via async DMA, 16B-chunk xor swizzle
  auto stage = [&](int kv, int buf) {
#pragma unroll
    for (int it = 0; it < 2; it++) {
      const int cI = it * 256 + tid;           // chunk index 0..511
      const int row = cI >> 3;
      const int c = (cI & 7) ^ (row & 7);
      const int dst = (it * 256 + wv * 64) * 8;
      async16(Kb + ((size_t)bh * 2048 + kv + row) * 64 + c * 8, &Ks[buf][dst]);
      async16(Vt + ((size_t)bh * 64 + row) * 2048 + kv + c * 8, &Vs[buf][dst]);
    }
  };

  stage(0, 0);

  for (int t = 0; t < 32; t++) {
    const int buf = t & 1;
    __syncthreads();                           // DMA(t) drained; all done reading buf^1
    if (t + 1 < 32) stage((t + 1) * 64, buf ^ 1);

    // ---- QK^T (S^T): sc[mt][nt]; key = nt*16 + qd*4 + r, q = q0 + mt*16 + rl ----
    f32x4 sc[2][4];
#pragma unroll
    for (int mt = 0; mt < 2; mt++)
#pragma unroll
      for (int nt = 0; nt < 4; nt++) sc[mt][nt] = f32x4{0.f, 0.f, 0.f, 0.f};
#pragma unroll
    for (int nt = 0; nt < 4; nt++) {
      const int ro = (nt * 16 + rl) * 64;
#pragma unroll
      for (int kk = 0; kk < 2; kk++) {
        const int cc = (((kk * 4 + qd) ^ (rl & 7)) << 3);
        f16x8 kh = *(const f16x8*)&Ks[buf][ro + cc];
#pragma unroll
        for (int mt = 0; mt < 2; mt++)
          sc[mt][nt] = mfma_f16(kh, qf[mt][kk], sc[mt][nt]);
      }
    }

    // ---- online softmax (scores already in exp2 domain) ----
#pragma unroll
    for (int mt = 0; mt < 2; mt++) {
      float mx = sc[mt][0][0];
#pragma unroll
      for (int nt = 0; nt < 4; nt++)
#pragma unroll
        for (int r = 0; r < 4; r++) mx = fmaxf(mx, sc[mt][nt][r]);
      mx = fmaxf(mx, __shfl_xor(mx, 16));
      mx = fmaxf(mx, __shfl_xor(mx, 32));
      const float mold = m_[mt];
      const float mnew = fmaxf(mold, mx);
      m_[mt] = mnew;
      float sm = 0.f;
#pragma unroll
      for (int nt = 0; nt < 4; nt++)
#pragma unroll
        for (int r = 0; r < 4; r++) {
          float p = EXP2F(sc[mt][nt][r] - mnew);
          sc[mt][nt][r] = p;
          sm += p;
        }
      sm += __shfl_xor(sm, 16);
      sm += __shfl_xor(sm, 32);
      if (__any(mnew > mold)) {                // max updated in some row: rescale
        const float al = EXP2F(mold - mnew);   // rows w/o update: exp2(0)=1
        l_[mt] = l_[mt] * al + sm;
#pragma unroll
        for (int jt = 0; jt < 4; jt++)
#pragma unroll
          for (int r = 0; r < 4; r++) o[mt][jt][r] *= al;
      } else {
        l_[mt] += sm;
      }

      // P^T (C-layout) -> Ps[q][key], b64 writes of 4 contiguous keys
#pragma unroll
      for (int nt = 0; nt < 4; nt++) {
        f16x4 pk = {(_Float16)sc[mt][nt][0], (_Float16)sc[mt][nt][1],
                    (_Float16)sc[mt][nt][2], (_Float16)sc[mt][nt][3]};
        *(f16x4*)&Ps[wv][mt * 16 + rl][nt * 16 + qd * 4] = pk;
      }
    }

    // ---- PV: O^T += V^T · P^T (per-wave Ps, no barrier) ----
#pragma unroll
    for (int kk2 = 0; kk2 < 2; kk2++) {
      f16x8 pf[2];
#pragma unroll
      for (int mt = 0; mt < 2; mt++)
        pf[mt] = *(const f16x8*)&Ps[wv][mt * 16 + rl][kk2 * 32 + qd * 8];
#pragma unroll
      for (int jt = 0; jt < 4; jt++) {
        const int cc = (((kk2 * 4 + qd) ^ (rl & 7)) << 3);
        f16x8 vv = *(const f16x8*)&Vs[buf][(jt * 16 + rl) * 64 + cc];
#pragma unroll
        for (int mt = 0; mt < 2; mt++)
          o[mt][jt] = mfma_f16(vv, pf[mt], o[mt][jt]);
      }
    }
  }

  // epilogue: O^T -> Xo[B,S,D]; lane holds d = jt*16 + qd*4 + r for q = mt*16+rl
  const int b = bh >> 4, hh = bh & 15;
#pragma unroll
  for (int mt = 0; mt < 2; mt++) {
    const float inv = 1.0f / l_[mt];
    const int q = q0 + mt * 16 + rl;
#pragma unroll
    for (int jt = 0; jt < 4; jt++) {
      f16x4 pk = {(_Float16)(o[mt][jt][0] * inv), (_Float16)(o[mt][jt][1] * inv),
                  (_Float16)(o[mt][jt][2] * inv), (_Float16)(o[mt][jt][3] * inv)};
      *(f16x4*)(Xo + ((size_t)(b * 2048 + q)) * 1024 + hh * 64 + jt * 16 + qd * 4) = pk;
    }
  }
}

// ---------------- output projection: fp16 GEMM -> fp32 out ----------------
__global__ __launch_bounds__(256) void gemm_out(
    const _Float16* __restrict__ A0,
    const _Float16* __restrict__ W0,
    const float* __restrict__ bias,
    float* __restrict__ out)
{
  __shared__ _Float16 LA[4096];
  __shared__ _Float16 LB[4096];
  const int tid = threadIdx.x;
  const int lane = tid & 63;
  const int wv = tid >> 6;
  const int wm = wv >> 1, wn = wv & 1;
  const int rl = lane & 15, qd = lane >> 4;
  const int m0 = blockIdx.y * 128, n0 = blockIdx.x * 128;

  f32x4 acc[4][4];
#pragma unroll
  for (int i = 0; i < 4; i++)
#pragma unroll
    for (int j = 0; j < 4; j++) acc[i][j] = f32x4{0.f, 0.f, 0.f, 0.f};

  const int srow = wv * 32 + (lane >> 2);
  const int scol = (lane & 3) * 8;

  for (int k0 = 0; k0 < 1024; k0 += 32) {
    const _Float16* ga = A0 + (size_t)(m0 + srow) * 1024 + k0 + scol;
    async16(ga, &LA[wv * 1024]);
    async16(ga + 16 * 1024, &LA[wv * 1024 + 512]);
    const _Float16* gb = W0 + (size_t)(n0 + srow) * 1024 + k0 + scol;
    async16(gb, &LB[wv * 1024]);
    async16(gb + 16 * 1024, &LB[wv * 1024 + 512]);
    __syncthreads();
    f16x8 af[4], bfr[4];
#pragma unroll
    for (int i = 0; i < 4; i++) af[i] = *(const f16x8*)&LA[(wm * 64 + i * 16 + rl) * 32 + qd * 8];
#pragma unroll
    for (int j = 0; j < 4; j++) bfr[j] = *(const f16x8*)&LB[(wn * 64 + j * 16 + rl) * 32 + qd * 8];
#pragma unroll
    for (int i = 0; i < 4; i++)
#pragma unroll
      for (int j = 0; j < 4; j++) acc[i][j] = mfma_f16(af[i], bfr[j], acc[i][j]);
    __syncthreads();
  }

#pragma unroll
  for (int j = 0; j < 4; j++) {
    const int nn = n0 + wn * 64 + j * 16 + rl;
    const float bj = bias[nn];
#pragma unroll
    for (int i = 0; i < 4; i++) {
      const int mm = m0 + wm * 64 + i * 16 + qd * 4;
#pragma unroll
      for (int r = 0; r < 4; r++)
        out[(size_t)(mm + r) * 1024 + nn] = acc[i][j][r] + bj;
    }
  }
}

// ---------------- launch ----------------
extern "C" void kernel_launch(void* const* d_in, const int* in_sizes, int n_in,
                              void* d_out, int out_size, void* d_ws, size_t ws_size,
                              hipStream_t stream) {
  const float* query = (const float*)d_in[0];
  const float* key   = (const float*)d_in[1];
  const float* value = (const float*)d_in[2];
  const float* Wq = (const float*)d_in[3];
  const float* bq = (const float*)d_in[4];
  const float* Wk = (const float*)d_in[5];
  const float* bk = (const float*)d_in[6];
  const float* Wv = (const float*)d_in[7];
  const float* bv = (const float*)d_in[8];
  const float* Wo = (const float*)d_in[9];
  const float* bo = (const float*)d_in[10];

  // workspace (half elements): 7*E8 + 4*M1 = 33.5M el = 67 MB
  _Float16* ws = (_Float16*)d_ws;
  _Float16* Xf = ws;                          // 3*E8: query,key,value fp16
  _Float16* Wf = ws + 3 * (size_t)E8;         // 4*M1: Wq,Wk,Wv,Wo fp16
  _Float16* Qh = Wf + 4 * (size_t)M1;         // E8 [B,H,S,HD] (pre-scaled)
  _Float16* Kh = Qh + (size_t)E8;             // E8 [B,H,S,HD]
  _Float16* Vt = Kh + (size_t)E8;             // E8 [B,H,HD,S]
  _Float16* Xa = Vt + (size_t)E8;             // E8 [B,S,D]

  prep_x<<<dim3(4096, 3), 256, 0, stream>>>(query, key, value, Xf);
  prep_w4<<<dim3(1024, 4), 256, 0, stream>>>(Wq, Wk, Wv, Wo, Wf);

  gemm_qkv<<<dim3(8, 32, 3), 256, 0, stream>>>(Xf, Wf, bq, bk, bv, Qh);
  attn_kernel<<<dim3(16, 32), 256, 0, stream>>>(Qh, Kh, Vt, Xa);
  gemm_out<<<dim3(8, 32), 256, 0, stream>>>(Xa, Wf + 3 * (size_t)M1, bo, (float*)d_out);
}

// Round 5
// 254.647 us; speedup vs baseline: 3.0304x; 1.0199x over previous
//
#include <hip/hip_runtime.h>
#include <stdint.h>
#include <stddef.h>

// Problem constants (B=2,S=2048,D=1024,H=16,HD=64)
#define SCALE_LOG2E 11.541560327111707f   // 8 * log2(e): folded into Q projection
#define E8 4194304                        // 4096*1024 plane (elements)
#define M1 1048576                        // 1024*1024 plane

typedef __attribute__((ext_vector_type(8))) _Float16 f16x8;
typedef __attribute__((ext_vector_type(4))) _Float16 f16x4;
typedef __attribute__((ext_vector_type(4))) float f32x4;

#if __has_builtin(__builtin_amdgcn_exp2f)
#define EXP2F(x) __builtin_amdgcn_exp2f(x)
#else
#define EXP2F(x) exp2f(x)
#endif

__device__ __forceinline__ f32x4 mfma_f16(f16x8 a, f16x8 b, f32x4 c) {
  return __builtin_amdgcn_mfma_f32_16x16x32_f16(a, b, c, 0, 0, 0);
}

// async global->LDS, 16B per lane. LDS dest is wave-uniform base + lane*16.
__device__ __forceinline__ void async16(const void* g, void* lds) {
  __builtin_amdgcn_global_load_lds(
      (const __attribute__((address_space(1))) unsigned int*)g,
      (__attribute__((address_space(3))) unsigned int*)lds, 16, 0, 0);
}

// ---------------- merged fp32 -> fp16 conversion (all 7 tensors) ----------------
// blocks 0..12287: X planes (query,key,value), 4096 blocks each.
// blocks 12288..16383: W planes (Wq,Wk,Wv,Wo), 1024 blocks each.
__global__ void prep_all(const float* __restrict__ q, const float* __restrict__ k,
                         const float* __restrict__ v,
                         const float* __restrict__ wq, const float* __restrict__ wk,
                         const float* __restrict__ wv, const float* __restrict__ wo,
                         _Float16* __restrict__ Xf, _Float16* __restrict__ Wf) {
  const int gid = blockIdx.x;
  const float* src;
  _Float16* dst;
  int i;
  if (gid < 12288) {
    const int z = gid >> 12;
    src = (z == 0) ? q : (z == 1) ? k : v;
    dst = Xf + (size_t)z * E8;
    i = (gid & 4095) * 256 + threadIdx.x;
  } else {
    const int g2 = gid - 12288;
    const int z = g2 >> 10;
    src = (z == 0) ? wq : (z == 1) ? wk : (z == 2) ? wv : wo;
    dst = Wf + (size_t)z * M1;
    i = (g2 & 1023) * 256 + threadIdx.x;
  }
  float4 x = ((const float4*)src)[i];
  f16x4 h = {(_Float16)x.x, (_Float16)x.y, (_Float16)x.z, (_Float16)x.w};
  ((f16x4*)dst)[i] = h;
}

// ---------------- merged Q/K/V projection: fp16 GEMM, LDS double-buffered ----------------
// z=0: Q (bias bq, *SCALE_LOG2E) -> [B,H,S,HD] at Of
// z=1: K (bias bk)               -> [B,H,S,HD] at Of+E8
// z=2: V (bias bv)               -> V^T [B,H,HD,S] at Of+2*E8
__global__ __launch_bounds__(256, 3) void gemm_qkv(
    const _Float16* __restrict__ Xf,    // 3 planes stride E8
    const _Float16* __restrict__ Wf,    // 4 planes stride M1
    const float* __restrict__ bq, const float* __restrict__ bk,
    const float* __restrict__ bv,
    _Float16* __restrict__ Of)
{
  __shared__ _Float16 LA[2][4096];
  __shared__ _Float16 LB[2][4096];
  const int z = blockIdx.z;
  const int tid = threadIdx.x;
  const int lane = tid & 63;
  const int wv = tid >> 6;
  const int wm = wv >> 1, wn = wv & 1;
  const int rl = lane & 15, qd = lane >> 4;
  const int m0 = blockIdx.y * 128, n0 = blockIdx.x * 128;

  const _Float16* A0 = Xf + (size_t)z * E8;
  const _Float16* W0 = Wf + (size_t)z * M1;
  const float* bias = (z == 0) ? bq : (z == 1) ? bk : bv;

  f32x4 acc[4][4];
#pragma unroll
  for (int i = 0; i < 4; i++)
#pragma unroll
    for (int j = 0; j < 4; j++) acc[i][j] = f32x4{0.f, 0.f, 0.f, 0.f};

  const int srow = wv * 32 + (lane >> 2);
  const int scol = (lane & 3) * 8;

  auto stage = [&](int k0, int buf) {
    const _Float16* ga = A0 + (size_t)(m0 + srow) * 1024 + k0 + scol;
    async16(ga, &LA[buf][wv * 1024]);
    async16(ga + 16 * 1024, &LA[buf][wv * 1024 + 512]);
    const _Float16* gb = W0 + (size_t)(n0 + srow) * 1024 + k0 + scol;
    async16(gb, &LB[buf][wv * 1024]);
    async16(gb + 16 * 1024, &LB[buf][wv * 1024 + 512]);
  };

  stage(0, 0);
  for (int t = 0; t < 32; t++) {
    const int buf = t & 1;
    __syncthreads();                          // DMA(t) drained; all done with buf^1
    if (t + 1 < 32) stage((t + 1) * 32, buf ^ 1);
    f16x8 af[4], bfr[4];
#pragma unroll
    for (int i = 0; i < 4; i++) af[i] = *(const f16x8*)&LA[buf][(wm * 64 + i * 16 + rl) * 32 + qd * 8];
#pragma unroll
    for (int j = 0; j < 4; j++) bfr[j] = *(const f16x8*)&LB[buf][(wn * 64 + j * 16 + rl) * 32 + qd * 8];
#pragma unroll
    for (int i = 0; i < 4; i++)
#pragma unroll
      for (int j = 0; j < 4; j++) acc[i][j] = mfma_f16(af[i], bfr[j], acc[i][j]);
  }

  if (z == 2) {
    // V^T epilogue: Vt[b,h,e,s], 4 contiguous s per store
#pragma unroll
    for (int j = 0; j < 4; j++) {
      const int nn = n0 + wn * 64 + j * 16 + rl;
      const float bj = bias[nn];
      const int hh = nn >> 6, e = nn & 63;
#pragma unroll
      for (int i = 0; i < 4; i++) {
        const int mm = m0 + wm * 64 + i * 16 + qd * 4;
        const int b = mm >> 11, s = mm & 2047;
        f16x4 pk = {(_Float16)(acc[i][j][0] + bj), (_Float16)(acc[i][j][1] + bj),
                    (_Float16)(acc[i][j][2] + bj), (_Float16)(acc[i][j][3] + bj)};
        *(f16x4*)(Of + 2 * (size_t)E8 + (((size_t)((b * 16 + hh) * 64 + e)) << 11) + s) = pk;
      }
    }
  } else {
    const float scl = (z == 0) ? SCALE_LOG2E : 1.0f;
    _Float16* base = Of + (size_t)z * E8;
#pragma unroll
    for (int j = 0; j < 4; j++) {
      const int nn = n0 + wn * 64 + j * 16 + rl;
      const float bj = bias[nn];
      const int hh = nn >> 6, e = nn & 63;
#pragma unroll
      for (int i = 0; i < 4; i++) {
        const int mm = m0 + wm * 64 + i * 16 + qd * 4;
        const int b = mm >> 11;
#pragma unroll
        for (int r = 0; r < 4; r++) {
          const int s = (mm + r) & 2047;
          base[((size_t)((b * 16 + hh) * 2048 + s) << 6) + e] =
              (_Float16)((acc[i][j][r] + bj) * scl);
        }
      }
    }
  }
}

// ---------------- flash attention v5 ----------------
// grid (32, 32): x = q-block (64 rows), y = bh. Block 256 (4 waves x 16 q).
// S^T = K·Q^T; O^T = V^T·P^T. K+V double-buffered DMA, 1 barrier/tile.
// Softmax: in-lane max -> exp starts immediately; cross-lane max overlaps;
// correction factor folded into f16 pack; l-reduction deferred to epilogue.
__global__ __launch_bounds__(256, 3) void attn_kernel(
    const _Float16* __restrict__ Qb,   // [B,H,S,HD], pre-scaled by 8*log2e
    const _Float16* __restrict__ Kb,   // [B,H,S,HD]
    const _Float16* __restrict__ Vt,   // [B,H,HD,S]
    _Float16* __restrict__ Xo)         // [B,S,D] fp16
{
  __shared__ _Float16 Ks[2][4096];     // dbuf [64 keys][64 d], xor-swizzled 16B chunks
  __shared__ _Float16 Vs[2][4096];     // dbuf [64 d][64 keys], same swizzle
  __shared__ _Float16 Ps[4][16][76];   // [wave][q][key], pitch 76 (0-conflict measured)
  const int tid = threadIdx.x;
  const int lane = tid & 63;
  const int wv = tid >> 6;
  const int rl = lane & 15, qd = lane >> 4;
  const int bh = blockIdx.y;
  const int q0 = blockIdx.x * 64 + wv * 16;

  // Q as B-operand fragments [kk]
  f16x8 qf[2];
#pragma unroll
  for (int kk = 0; kk < 2; kk++)
    qf[kk] = *(const f16x8*)(Qb + ((size_t)bh * 2048 + q0 + rl) * 64 + kk * 32 + qd * 8);

  float m_ = -1e30f, l_ = 0.f;         // l_ is a per-lane partial (reduced in epilogue)
  f32x4 o[4];
#pragma unroll
  for (int jt = 0; jt < 4; jt++) o[jt] = f32x4{0.f, 0.f, 0.f, 0.f};

  // stage K and V tiles (8 KB each) via async DMA, 16B-chunk xor swizzle
  auto stage = [&](int kv, int buf) {
#pragma unroll
    for (int it = 0; it < 2; it++) {
      const int cI = it * 256 + tid;           // chunk index 0..511
      const int row = cI >> 3;
      const int c = (cI & 7) ^ (row & 7);
      const int dst = (it * 256 + wv * 64) * 8;
      async16(Kb + ((size_t)bh * 2048 + kv + row) * 64 + c * 8, &Ks[buf][dst]);
      async16(Vt + ((size_t)bh * 64 + row) * 2048 + kv + c * 8, &Vs[buf][dst]);
    }
  };

  stage(0, 0);

  for (int t = 0; t < 32; t++) {
    const int buf = t & 1;
    __syncthreads();                           // DMA(t) drained; all done reading buf^1
    if (t + 1 < 32) stage((t + 1) * 64, buf ^ 1);

    // ---- QK^T (S^T): sc[nt]; key = nt*16 + qd*4 + r, q = q0 + rl ----
    f32x4 sc[4];
#pragma unroll
    for (int nt = 0; nt < 4; nt++) sc[nt] = f32x4{0.f, 0.f, 0.f, 0.f};
#pragma unroll
    for (int nt = 0; nt < 4; nt++) {
      const int ro = (nt * 16 + rl) * 64;
#pragma unroll
      for (int kk = 0; kk < 2; kk++) {
        const int cc = (((kk * 4 + qd) ^ (rl & 7)) << 3);
        f16x8 kh = *(const f16x8*)&Ks[buf][ro + cc];
        sc[nt] = mfma_f16(kh, qf[kk], sc[nt]);
      }
    }

    // ---- online softmax, in-lane-max-first ----
    float mloc = sc[0][0];
#pragma unroll
    for (int nt = 0; nt < 4; nt++)
#pragma unroll
      for (int r = 0; r < 4; r++) mloc = fmaxf(mloc, sc[nt][r]);
    // exp with local max starts now; cross-lane max overlaps in the scalar/LDS pipes
    float mx = fmaxf(mloc, __shfl_xor(mloc, 16));
    mx = fmaxf(mx, __shfl_xor(mx, 32));
    float sm = 0.f;
#pragma unroll
    for (int nt = 0; nt < 4; nt++)
#pragma unroll
      for (int r = 0; r < 4; r++) {
        float p = EXP2F(sc[nt][r] - mloc);
        sc[nt][r] = p;
        sm += p;
      }
    const float mold = m_;
    const float mnew = fmaxf(mold, mx);
    m_ = mnew;
    const float cf = EXP2F(mloc - mnew);       // per-lane correction
    if (__any(mnew > mold)) {                  // running max advanced somewhere
      const float al = EXP2F(mold - mnew);     // row-wide (1.0 where unchanged)
      l_ = l_ * al + sm * cf;
#pragma unroll
      for (int jt = 0; jt < 4; jt++)
#pragma unroll
        for (int r = 0; r < 4; r++) o[jt][r] *= al;
    } else {
      l_ += sm * cf;
    }

    // P^T (C-layout) -> Ps[q][key], cf folded into the pack
#pragma unroll
    for (int nt = 0; nt < 4; nt++) {
      f16x4 pk = {(_Float16)(sc[nt][0] * cf), (_Float16)(sc[nt][1] * cf),
                  (_Float16)(sc[nt][2] * cf), (_Float16)(sc[nt][3] * cf)};
      *(f16x4*)&Ps[wv][rl][nt * 16 + qd * 4] = pk;
    }

    // ---- PV: O^T += V^T · P^T (per-wave Ps, no barrier) ----
#pragma unroll
    for (int kk2 = 0; kk2 < 2; kk2++) {
      f16x8 pf = *(const f16x8*)&Ps[wv][rl][kk2 * 32 + qd * 8];
#pragma unroll
      for (int jt = 0; jt < 4; jt++) {
        const int cc = (((kk2 * 4 + qd) ^ (rl & 7)) << 3);
        f16x8 vv = *(const f16x8*)&Vs[buf][(jt * 16 + rl) * 64 + cc];
        o[jt] = mfma_f16(vv, pf, o[jt]);
      }
    }
  }

  // epilogue: reduce l over the 4 qd-lanes, then O^T -> Xo[B,S,D]
  float lt = l_ + __shfl_xor(l_, 16);
  lt += __shfl_xor(lt, 32);
  const float inv = 1.0f / lt;
  const int b = bh >> 4, hh = bh & 15;
  const int q = q0 + rl;
#pragma unroll
  for (int jt = 0; jt < 4; jt++) {
    f16x4 pk = {(_Float16)(o[jt][0] * inv), (_Float16)(o[jt][1] * inv),
                (_Float16)(o[jt][2] * inv), (_Float16)(o[jt][3] * inv)};
    *(f16x4*)(Xo + ((size_t)(b * 2048 + q)) * 1024 + hh * 64 + jt * 16 + qd * 4) = pk;
  }
}

// ---------------- output projection: 64x128 tile, dbuf, fp32 out ----------------
__global__ __launch_bounds__(256, 2) void gemm_out(
    const _Float16* __restrict__ A0,
    const _Float16* __restrict__ W0,
    const float* __restrict__ bias,
    float* __restrict__ out)
{
  __shared__ _Float16 LA[2][2048];   // 64 x 32
  __shared__ _Float16 LB[2][4096];   // 128 x 32
  const int tid = threadIdx.x;
  const int lane = tid & 63;
  const int wv = tid >> 6;
  const int wm = wv >> 1, wn = wv & 1;
  const int rl = lane & 15, qd = lane >> 4;
  const int m0 = blockIdx.y * 64, n0 = blockIdx.x * 128;

  f32x4 acc[2][4];
#pragma unroll
  for (int i = 0; i < 2; i++)
#pragma unroll
    for (int j = 0; j < 4; j++) acc[i][j] = f32x4{0.f, 0.f, 0.f, 0.f};

  auto stage = [&](int k0, int buf) {
    {  // A: 256 chunks, 1 per thread
      const int row = tid >> 2, c = tid & 3;
      async16(A0 + (size_t)(m0 + row) * 1024 + k0 + c * 8, &LA[buf][wv * 512]);
    }
#pragma unroll
    for (int it = 0; it < 2; it++) {  // B: 512 chunks, 2 per thread
      const int cI = it * 256 + tid;
      const int row = cI >> 2, c = cI & 3;
      async16(W0 + (size_t)(n0 + row) * 1024 + k0 + c * 8,
              &LB[buf][it * 2048 + wv * 512]);
    }
  };

  stage(0, 0);
  for (int t = 0; t < 32; t++) {
    const int buf = t & 1;
    __syncthreads();
    if (t + 1 < 32) stage((t + 1) * 32, buf ^ 1);
    f16x8 af[2], bfr[4];
#pragma unroll
    for (int i = 0; i < 2; i++) af[i] = *(const f16x8*)&LA[buf][(wm * 32 + i * 16 + rl) * 32 + qd * 8];
#pragma unroll
    for (int j = 0; j < 4; j++) bfr[j] = *(const f16x8*)&LB[buf][(wn * 64 + j * 16 + rl) * 32 + qd * 8];
#pragma unroll
    for (int i = 0; i < 2; i++)
#pragma unroll
      for (int j = 0; j < 4; j++) acc[i][j] = mfma_f16(af[i], bfr[j], acc[i][j]);
  }

#pragma unroll
  for (int j = 0; j < 4; j++) {
    const int nn = n0 + wn * 64 + j * 16 + rl;
    const float bj = bias[nn];
#pragma unroll
    for (int i = 0; i < 2; i++) {
      const int mm = m0 + wm * 32 + i * 16 + qd * 4;
#pragma unroll
      for (int r = 0; r < 4; r++)
        out[(size_t)(mm + r) * 1024 + nn] = acc[i][j][r] + bj;
    }
  }
}

// ---------------- launch ----------------
extern "C" void kernel_launch(void* const* d_in, const int* in_sizes, int n_in,
                              void* d_out, int out_size, void* d_ws, size_t ws_size,
                              hipStream_t stream) {
  const float* query = (const float*)d_in[0];
  const float* key   = (const float*)d_in[1];
  const float* value = (const float*)d_in[2];
  const float* Wq = (const float*)d_in[3];
  const float* bq = (const float*)d_in[4];
  const float* Wk = (const float*)d_in[5];
  const float* bk = (const float*)d_in[6];
  const float* Wv = (const float*)d_in[7];
  const float* bv = (const float*)d_in[8];
  const float* Wo = (const float*)d_in[9];
  const float* bo = (const float*)d_in[10];

  // workspace (half elements): 7*E8 + 4*M1 = 33.5M el = 67 MB
  _Float16* ws = (_Float16*)d_ws;
  _Float16* Xf = ws;                          // 3*E8: query,key,value fp16
  _Float16* Wf = ws + 3 * (size_t)E8;         // 4*M1: Wq,Wk,Wv,Wo fp16
  _Float16* Qh = Wf + 4 * (size_t)M1;         // E8 [B,H,S,HD] (pre-scaled)
  _Float16* Kh = Qh + (size_t)E8;             // E8 [B,H,S,HD]
  _Float16* Vt = Kh + (size_t)E8;             // E8 [B,H,HD,S]
  _Float16* Xa = Vt + (size_t)E8;             // E8 [B,S,D]

  prep_all<<<16384, 256, 0, stream>>>(query, key, value, Wq, Wk, Wv, Wo, Xf, Wf);
  gemm_qkv<<<dim3(8, 32, 3), 256, 0, stream>>>(Xf, Wf, bq, bk, bv, Qh);
  attn_kernel<<<dim3(32, 32), 256, 0, stream>>>(Qh, Kh, Vt, Xa);
  gemm_out<<<dim3(8, 64), 256, 0, stream>>>(Xa, Wf + 3 * (size_t)M1, bo, (float*)d_out);
}

// Round 6
// 245.724 us; speedup vs baseline: 3.1404x; 1.0363x over previous
//
#include <hip/hip_runtime.h>
#include <stdint.h>
#include <stddef.h>

// Problem constants (B=2,S=2048,D=1024,H=16,HD=64)
#define SCALE_LOG2E 11.541560327111707f   // 8 * log2(e): folded into Q projection
#define E8 4194304                        // 4096*1024 plane (elements)
#define M1 1048576                        // 1024*1024 plane
#define NROW 65536                        // B*H*S rows

typedef __attribute__((ext_vector_type(8))) _Float16 f16x8;
typedef __attribute__((ext_vector_type(4))) _Float16 f16x4;
typedef __attribute__((ext_vector_type(4))) float f32x4;

#if __has_builtin(__builtin_amdgcn_exp2f)
#define EXP2F(x) __builtin_amdgcn_exp2f(x)
#else
#define EXP2F(x) exp2f(x)
#endif

__device__ __forceinline__ f32x4 mfma_f16(f16x8 a, f16x8 b, f32x4 c) {
  return __builtin_amdgcn_mfma_f32_16x16x32_f16(a, b, c, 0, 0, 0);
}

// async global->LDS, 16B per lane. LDS dest is wave-uniform base + lane*16.
__device__ __forceinline__ void async16(const void* g, void* lds) {
  __builtin_amdgcn_global_load_lds(
      (const __attribute__((address_space(1))) unsigned int*)g,
      (__attribute__((address_space(3))) unsigned int*)lds, 16, 0, 0);
}

// ---------------- merged fp32 -> fp16 conversion (all 7 tensors) ----------------
__global__ void prep_all(const float* __restrict__ q, const float* __restrict__ k,
                         const float* __restrict__ v,
                         const float* __restrict__ wq, const float* __restrict__ wk,
                         const float* __restrict__ wv, const float* __restrict__ wo,
                         _Float16* __restrict__ Xf, _Float16* __restrict__ Wf) {
  const int gid = blockIdx.x;
  const float* src;
  _Float16* dst;
  int i;
  if (gid < 12288) {
    const int z = gid >> 12;
    src = (z == 0) ? q : (z == 1) ? k : v;
    dst = Xf + (size_t)z * E8;
    i = (gid & 4095) * 256 + threadIdx.x;
  } else {
    const int g2 = gid - 12288;
    const int z = g2 >> 10;
    src = (z == 0) ? wq : (z == 1) ? wk : (z == 2) ? wv : wo;
    dst = Wf + (size_t)z * M1;
    i = (g2 & 1023) * 256 + threadIdx.x;
  }
  float4 x = ((const float4*)src)[i];
  f16x4 h = {(_Float16)x.x, (_Float16)x.y, (_Float16)x.z, (_Float16)x.w};
  ((f16x4*)dst)[i] = h;
}

// ---------------- merged Q/K/V projection: fp16 GEMM, LDS double-buffered ----------------
// z=0: Q (bias bq, *SCALE_LOG2E) -> [B,H,S,HD] at Of
// z=1: K (bias bk)               -> [B,H,S,HD] at Of+E8
// z=2: V (bias bv)               -> V^T [B,H,HD,S] at Of+2*E8
__global__ __launch_bounds__(256, 3) void gemm_qkv(
    const _Float16* __restrict__ Xf,    // 3 planes stride E8
    const _Float16* __restrict__ Wf,    // 4 planes stride M1
    const float* __restrict__ bq, const float* __restrict__ bk,
    const float* __restrict__ bv,
    _Float16* __restrict__ Of)
{
  __shared__ _Float16 SMEM[16384];      // staging dbuf (2x4096 A + 2x4096 B) / epilogue Ct
  _Float16* LA = SMEM;                  // [2][4096]
  _Float16* LB = SMEM + 8192;           // [2][4096]
  const int z = blockIdx.z;
  const int tid = threadIdx.x;
  const int lane = tid & 63;
  const int wv = tid >> 6;
  const int wm = wv >> 1, wn = wv & 1;
  const int rl = lane & 15, qd = lane >> 4;
  const int m0 = blockIdx.y * 128, n0 = blockIdx.x * 128;

  const _Float16* A0 = Xf + (size_t)z * E8;
  const _Float16* W0 = Wf + (size_t)z * M1;
  const float* bias = (z == 0) ? bq : (z == 1) ? bk : bv;

  f32x4 acc[4][4];
#pragma unroll
  for (int i = 0; i < 4; i++)
#pragma unroll
    for (int j = 0; j < 4; j++) acc[i][j] = f32x4{0.f, 0.f, 0.f, 0.f};

  const int srow = wv * 32 + (lane >> 2);
  const int scol = (lane & 3) * 8;

  auto stage = [&](int k0, int buf) {
    const _Float16* ga = A0 + (size_t)(m0 + srow) * 1024 + k0 + scol;
    async16(ga, &LA[buf * 4096 + wv * 1024]);
    async16(ga + 16 * 1024, &LA[buf * 4096 + wv * 1024 + 512]);
    const _Float16* gb = W0 + (size_t)(n0 + srow) * 1024 + k0 + scol;
    async16(gb, &LB[buf * 4096 + wv * 1024]);
    async16(gb + 16 * 1024, &LB[buf * 4096 + wv * 1024 + 512]);
  };

  stage(0, 0);
  for (int t = 0; t < 32; t++) {
    const int buf = t & 1;
    __syncthreads();                          // DMA(t) drained; all done with buf^1
    if (t + 1 < 32) stage((t + 1) * 32, buf ^ 1);
    f16x8 af[4], bfr[4];
#pragma unroll
    for (int i = 0; i < 4; i++) af[i] = *(const f16x8*)&LA[buf * 4096 + (wm * 64 + i * 16 + rl) * 32 + qd * 8];
#pragma unroll
    for (int j = 0; j < 4; j++) bfr[j] = *(const f16x8*)&LB[buf * 4096 + (wn * 64 + j * 16 + rl) * 32 + qd * 8];
#pragma unroll
    for (int i = 0; i < 4; i++)
#pragma unroll
      for (int j = 0; j < 4; j++) acc[i][j] = mfma_f16(af[i], bfr[j], acc[i][j]);
  }

  if (z == 2) {
    // V^T epilogue: Vt[b,h,e,s], 4 contiguous s per store
#pragma unroll
    for (int j = 0; j < 4; j++) {
      const int nn = n0 + wn * 64 + j * 16 + rl;
      const float bj = bias[nn];
      const int hh = nn >> 6, e = nn & 63;
#pragma unroll
      for (int i = 0; i < 4; i++) {
        const int mm = m0 + wm * 64 + i * 16 + qd * 4;
        const int b = mm >> 11, s = mm & 2047;
        f16x4 pk = {(_Float16)(acc[i][j][0] + bj), (_Float16)(acc[i][j][1] + bj),
                    (_Float16)(acc[i][j][2] + bj), (_Float16)(acc[i][j][3] + bj)};
        *(f16x4*)(Of + 2 * (size_t)E8 + (((size_t)((b * 16 + hh) * 64 + e)) << 11) + s) = pk;
      }
    }
  } else {
    // LDS-transposed coalesced epilogue: Ct[128][128] with qd-xor column swizzle
    const float scl = (z == 0) ? SCALE_LOG2E : 1.0f;
    _Float16* base = Of + (size_t)z * E8;
    __syncthreads();                          // staging LDS now free
#pragma unroll
    for (int j = 0; j < 4; j++) {
      const int nl = wn * 64 + j * 16 + rl;
      const float bj = bias[n0 + nl];
#pragma unroll
      for (int i = 0; i < 4; i++) {
        const int ml = wm * 64 + i * 16 + qd * 4;
        const int np = nl ^ (qd << 4);        // (m>>2)&3 == qd here
#pragma unroll
        for (int r = 0; r < 4; r++)
          SMEM[(ml + r) * 128 + np] = (_Float16)((acc[i][j][r] + bj) * scl);
      }
    }
    __syncthreads();
#pragma unroll
    for (int it2 = 0; it2 < 8; it2++) {
      const int m = (it2 * 256 + tid) >> 4;   // 0..127
      const int col8 = (tid & 15) * 8;
      const int np = col8 ^ (((m >> 2) & 3) << 4);
      f16x8 vrow = *(const f16x8*)&SMEM[m * 128 + np];
      const int sg = m0 + m;
      const int b = sg >> 11, s = sg & 2047;
      const int nn = n0 + col8;
      const int hh = nn >> 6, e = nn & 63;
      *(f16x8*)(base + (((size_t)((b * 16 + hh) * 2048 + s)) << 6) + e) = vrow;
    }
  }
}

// ---------------- flash attention v6: split-KV, mt=2, dbuf DMA ----------------
// grid (16, 2, 32): x = q-block (128 rows), y = kv half (1024 keys), z = bh.
// Block 256 (4 waves x 32 q). S^T = K·Q^T; O^T = V^T·P^T.
// Emits partial (o f32, m, l) per half; merge_kernel combines.
__global__ __launch_bounds__(256, 3) void attn_kernel(
    const _Float16* __restrict__ Qb,   // [B,H,S,HD], pre-scaled by 8*log2e
    const _Float16* __restrict__ Kb,   // [B,H,S,HD]
    const _Float16* __restrict__ Vt,   // [B,H,HD,S]
    float* __restrict__ Op,            // [2][NROW][64] f32 partial O^T (unnormalized)
    float2* __restrict__ ML)           // [2][NROW] (m, l)
{
  __shared__ _Float16 Ks[2][4096];     // dbuf [64 keys][64 d], xor-swizzled 16B chunks
  __shared__ _Float16 Vs[2][4096];     // dbuf [64 d][64 keys], same swizzle
  __shared__ _Float16 Ps[4][32][76];   // [wave][q][key], pitch 76 (0-conflict measured)
  const int tid = threadIdx.x;
  const int lane = tid & 63;
  const int wv = tid >> 6;
  const int rl = lane & 15, qd = lane >> 4;
  const int bh = blockIdx.z;
  const int half = blockIdx.y;
  const int kvb = half * 1024;
  const int q0 = blockIdx.x * 128 + wv * 32;

  // Q as B-operand fragments [mt][kk]
  f16x8 qf[2][2];
#pragma unroll
  for (int mt = 0; mt < 2; mt++)
#pragma unroll
    for (int kk = 0; kk < 2; kk++)
      qf[mt][kk] = *(const f16x8*)(Qb + ((size_t)bh * 2048 + q0 + mt * 16 + rl) * 64 +
                                   kk * 32 + qd * 8);

  float m_[2] = {-1e30f, -1e30f}, l_[2] = {0.f, 0.f};  // l_ per-lane partial
  f32x4 o[2][4];
#pragma unroll
  for (int mt = 0; mt < 2; mt++)
#pragma unroll
    for (int jt = 0; jt < 4; jt++) o[mt][jt] = f32x4{0.f, 0.f, 0.f, 0.f};

  // stage K and V tiles (8 KB each) via async DMA, 16B-chunk xor swizzle
  auto stage = [&](int kv, int buf) {
#pragma unroll
    for (int it = 0; it < 2; it++) {
      const int cI = it * 256 + tid;           // chunk index 0..511
      const int row = cI >> 3;
      const int c = (cI & 7) ^ (row & 7);
      const int dst = (it * 256 + wv * 64) * 8;
      async16(Kb + ((size_t)bh * 2048 + kv + row) * 64 + c * 8, &Ks[buf][dst]);
      async16(Vt + ((size_t)bh * 64 + row) * 2048 + kv + c * 8, &Vs[buf][dst]);
    }
  };

  stage(kvb, 0);

  for (int t = 0; t < 16; t++) {
    const int buf = t & 1;
    __syncthreads();                           // DMA(t) drained; all done reading buf^1
    if (t + 1 < 16) stage(kvb + (t + 1) * 64, buf ^ 1);

    // ---- QK^T (S^T): sc[mt][nt]; key = nt*16 + qd*4 + r, q = q0 + mt*16 + rl ----
    f32x4 sc[2][4];
#pragma unroll
    for (int mt = 0; mt < 2; mt++)
#pragma unroll
      for (int nt = 0; nt < 4; nt++) sc[mt][nt] = f32x4{0.f, 0.f, 0.f, 0.f};
#pragma unroll
    for (int nt = 0; nt < 4; nt++) {
      const int ro = (nt * 16 + rl) * 64;
#pragma unroll
      for (int kk = 0; kk < 2; kk++) {
        const int cc = (((kk * 4 + qd) ^ (rl & 7)) << 3);
        f16x8 kh = *(const f16x8*)&Ks[buf][ro + cc];
#pragma unroll
        for (int mt = 0; mt < 2; mt++)
          sc[mt][nt] = mfma_f16(kh, qf[mt][kk], sc[mt][nt]);
      }
    }

    // ---- online softmax (exp2 domain), in-lane-max-first, per-lane l partial ----
#pragma unroll
    for (int mt = 0; mt < 2; mt++) {
      float mloc = sc[mt][0][0];
#pragma unroll
      for (int nt = 0; nt < 4; nt++)
#pragma unroll
        for (int r = 0; r < 4; r++) mloc = fmaxf(mloc, sc[mt][nt][r]);
      float mx = fmaxf(mloc, __shfl_xor(mloc, 16));
      mx = fmaxf(mx, __shfl_xor(mx, 32));
      float sm = 0.f;
#pragma unroll
      for (int nt = 0; nt < 4; nt++)
#pragma unroll
        for (int r = 0; r < 4; r++) {
          float p = EXP2F(sc[mt][nt][r] - mloc);
          sc[mt][nt][r] = p;
          sm += p;
        }
      const float mold = m_[mt];
      const float mnew = fmaxf(mold, mx);
      m_[mt] = mnew;
      const float cf = EXP2F(mloc - mnew);     // per-lane correction
      if (__any(mnew > mold)) {
        const float al = EXP2F(mold - mnew);   // row-wide (1.0 where unchanged)
        l_[mt] = l_[mt] * al + sm * cf;
#pragma unroll
        for (int jt = 0; jt < 4; jt++)
#pragma unroll
          for (int r = 0; r < 4; r++) o[mt][jt][r] *= al;
      } else {
        l_[mt] += sm * cf;
      }

      // P^T (C-layout) -> Ps[q][key], cf folded into the pack
#pragma unroll
      for (int nt = 0; nt < 4; nt++) {
        f16x4 pk = {(_Float16)(sc[mt][nt][0] * cf), (_Float16)(sc[mt][nt][1] * cf),
                    (_Float16)(sc[mt][nt][2] * cf), (_Float16)(sc[mt][nt][3] * cf)};
        *(f16x4*)&Ps[wv][mt * 16 + rl][nt * 16 + qd * 4] = pk;
      }
    }

    // ---- PV: O^T += V^T · P^T (per-wave Ps, no barrier) ----
#pragma unroll
    for (int kk2 = 0; kk2 < 2; kk2++) {
      f16x8 pf[2];
#pragma unroll
      for (int mt = 0; mt < 2; mt++)
        pf[mt] = *(const f16x8*)&Ps[wv][mt * 16 + rl][kk2 * 32 + qd * 8];
#pragma unroll
      for (int jt = 0; jt < 4; jt++) {
        const int cc = (((kk2 * 4 + qd) ^ (rl & 7)) << 3);
        f16x8 vv = *(const f16x8*)&Vs[buf][(jt * 16 + rl) * 64 + cc];
#pragma unroll
        for (int mt = 0; mt < 2; mt++)
          o[mt][jt] = mfma_f16(vv, pf[mt], o[mt][jt]);
      }
    }
  }

  // epilogue: write partials (unnormalized). lane holds d = jt*16 + qd*4 + r.
#pragma unroll
  for (int mt = 0; mt < 2; mt++) {
    float lt = l_[mt] + __shfl_xor(l_[mt], 16);
    lt += __shfl_xor(lt, 32);
    const size_t row = (size_t)bh * 2048 + q0 + mt * 16 + rl;
    float* op = Op + ((size_t)half * NROW + row) * 64;
#pragma unroll
    for (int jt = 0; jt < 4; jt++)
      *(f32x4*)(op + jt * 16 + qd * 4) = o[mt][jt];
    if (qd == 0) ML[(size_t)half * NROW + row] = make_float2(m_[mt], lt);
  }
}

// ---------------- merge the two KV halves ----------------
// block 256 = 16 rows x 16 threads; thread handles 4 d.
__global__ void merge_kernel(const float* __restrict__ Op,
                             const float2* __restrict__ ML,
                             _Float16* __restrict__ Xo) {
  const int t = threadIdx.x;
  const int row = blockIdx.x * 16 + (t >> 4);
  const int d0 = (t & 15) * 4;
  const float2 ml1 = ML[row];
  const float2 ml2 = ML[NROW + row];
  const float m = fmaxf(ml1.x, ml2.x);
  const float w1 = EXP2F(ml1.x - m), w2 = EXP2F(ml2.x - m);
  const float inv = 1.0f / (ml1.y * w1 + ml2.y * w2);
  const float4 o1 = *(const float4*)(Op + (size_t)row * 64 + d0);
  const float4 o2 = *(const float4*)(Op + (size_t)NROW * 64 + (size_t)row * 64 + d0);
  const int bh = row >> 11, q = row & 2047;
  const int b = bh >> 4, hh = bh & 15;
  f16x4 pk = {(_Float16)((o1.x * w1 + o2.x * w2) * inv),
              (_Float16)((o1.y * w1 + o2.y * w2) * inv),
              (_Float16)((o1.z * w1 + o2.z * w2) * inv),
              (_Float16)((o1.w * w1 + o2.w * w2) * inv)};
  *(f16x4*)(Xo + ((size_t)(b * 2048 + q)) * 1024 + hh * 64 + d0) = pk;
}

// ---------------- output projection: 64x128 tile, dbuf, fp32 out ----------------
__global__ __launch_bounds__(256, 2) void gemm_out(
    const _Float16* __restrict__ A0,
    const _Float16* __restrict__ W0,
    const float* __restrict__ bias,
    float* __restrict__ out)
{
  __shared__ _Float16 LA[2][2048];   // 64 x 32
  __shared__ _Float16 LB[2][4096];   // 128 x 32
  const int tid = threadIdx.x;
  const int lane = tid & 63;
  const int wv = tid >> 6;
  const int wm = wv >> 1, wn = wv & 1;
  const int rl = lane & 15, qd = lane >> 4;
  const int m0 = blockIdx.y * 64, n0 = blockIdx.x * 128;

  f32x4 acc[2][4];
#pragma unroll
  for (int i = 0; i < 2; i++)
#pragma unroll
    for (int j = 0; j < 4; j++) acc[i][j] = f32x4{0.f, 0.f, 0.f, 0.f};

  auto stage = [&](int k0, int buf) {
    {  // A: 256 chunks, 1 per thread
      const int row = tid >> 2, c = tid & 3;
      async16(A0 + (size_t)(m0 + row) * 1024 + k0 + c * 8, &LA[buf][wv * 512]);
    }
#pragma unroll
    for (int it = 0; it < 2; it++) {  // B: 512 chunks, 2 per thread
      const int cI = it * 256 + tid;
      const int row = cI >> 2, c = cI & 3;
      async16(W0 + (size_t)(n0 + row) * 1024 + k0 + c * 8,
              &LB[buf][it * 2048 + wv * 512]);
    }
  };

  stage(0, 0);
  for (int t = 0; t < 32; t++) {
    const int buf = t & 1;
    __syncthreads();
    if (t + 1 < 32) stage((t + 1) * 32, buf ^ 1);
    f16x8 af[2], bfr[4];
#pragma unroll
    for (int i = 0; i < 2; i++) af[i] = *(const f16x8*)&LA[buf][(wm * 32 + i * 16 + rl) * 32 + qd * 8];
#pragma unroll
    for (int j = 0; j < 4; j++) bfr[j] = *(const f16x8*)&LB[buf][(wn * 64 + j * 16 + rl) * 32 + qd * 8];
#pragma unroll
    for (int i = 0; i < 2; i++)
#pragma unroll
      for (int j = 0; j < 4; j++) acc[i][j] = mfma_f16(af[i], bfr[j], acc[i][j]);
  }

#pragma unroll
  for (int j = 0; j < 4; j++) {
    const int nn = n0 + wn * 64 + j * 16 + rl;
    const float bj = bias[nn];
#pragma unroll
    for (int i = 0; i < 2; i++) {
      const int mm = m0 + wm * 32 + i * 16 + qd * 4;
#pragma unroll
      for (int r = 0; r < 4; r++)
        out[(size_t)(mm + r) * 1024 + nn] = acc[i][j][r] + bj;
    }
  }
}

// ---------------- launch ----------------
extern "C" void kernel_launch(void* const* d_in, const int* in_sizes, int n_in,
                              void* d_out, int out_size, void* d_ws, size_t ws_size,
                              hipStream_t stream) {
  const float* query = (const float*)d_in[0];
  const float* key   = (const float*)d_in[1];
  const float* value = (const float*)d_in[2];
  const float* Wq = (const float*)d_in[3];
  const float* bq = (const float*)d_in[4];
  const float* Wk = (const float*)d_in[5];
  const float* bk = (const float*)d_in[6];
  const float* Wv = (const float*)d_in[7];
  const float* bv = (const float*)d_in[8];
  const float* Wo = (const float*)d_in[9];
  const float* bo = (const float*)d_in[10];

  // workspace: f16 region 67 MB + f32 partials 34.6 MB
  _Float16* ws = (_Float16*)d_ws;
  _Float16* Xf = ws;                          // 3*E8: query,key,value fp16
  _Float16* Wf = ws + 3 * (size_t)E8;         // 4*M1: Wq,Wk,Wv,Wo fp16
  _Float16* Qh = Wf + 4 * (size_t)M1;         // E8 [B,H,S,HD] (pre-scaled)
  _Float16* Kh = Qh + (size_t)E8;             // E8 [B,H,S,HD]
  _Float16* Vt = Kh + (size_t)E8;             // E8 [B,H,HD,S]
  _Float16* Xa = Vt + (size_t)E8;             // E8 [B,S,D]
  float*    Op = (float*)(Xa + (size_t)E8);   // [2][NROW][64] f32
  float2*   ML = (float2*)(Op + 2 * (size_t)NROW * 64);  // [2][NROW]

  prep_all<<<16384, 256, 0, stream>>>(query, key, value, Wq, Wk, Wv, Wo, Xf, Wf);
  gemm_qkv<<<dim3(8, 32, 3), 256, 0, stream>>>(Xf, Wf, bq, bk, bv, Qh);
  attn_kernel<<<dim3(16, 2, 32), 256, 0, stream>>>(Qh, Kh, Vt, Op, ML);
  merge_kernel<<<4096, 256, 0, stream>>>(Op, ML, Xa);
  gemm_out<<<dim3(8, 64), 256, 0, stream>>>(Xa, Wf + 3 * (size_t)M1, bo, (float*)d_out);
}